// Round 8
// baseline (254.761 us; speedup 1.0000x reference)
//
#include <hip/hip_runtime.h>

typedef unsigned short u16;
typedef unsigned int   u32;
typedef unsigned long long u64;
typedef short s16;

using f32x4  = __attribute__((ext_vector_type(4))) float;
using bf16x8 = __attribute__((ext_vector_type(8))) __bf16;
using bf16x4 = __attribute__((ext_vector_type(4))) __bf16;
using u16x8  = __attribute__((ext_vector_type(8))) u16;
using u16x4  = __attribute__((ext_vector_type(4))) u16;
using s16x4  = __attribute__((ext_vector_type(4))) s16;

#define LOG2E 1.4426950408889634f

// float -> bf16 with round-to-nearest-even (cold paths)
__device__ __forceinline__ u16 f2bf(float f) {
  u32 u = __builtin_bit_cast(u32, f);
  u32 r = u + 0x7fffu + ((u >> 16) & 1u);
  return (u16)(r >> 16);
}

// raw v_exp_f32 (OCML exp2f carries denormal fixup = ~10 VALU per call)
__device__ __forceinline__ float ex2(float x) {
#if __has_builtin(__builtin_amdgcn_exp2f)
  return __builtin_amdgcn_exp2f(x);
#else
  return exp2f(x);
#endif
}

// native __bf16 casts: compiler emits v_cvt_pk_bf16_f32 pairs
__device__ __forceinline__ u16x4 pack4(float p0, float p1, float p2, float p3) {
  bf16x4 b = {(__bf16)p0, (__bf16)p1, (__bf16)p2, (__bf16)p3};
  return __builtin_bit_cast(u16x4, b);
}

// 8x f32 -> bf16 RNE (v_cvt_pk_bf16_f32; R1 evidence: bit-identical to f2bf)
__device__ __forceinline__ u16x8 cvt8(f32x4 a, f32x4 b) {
  bf16x8 r = {(__bf16)a[0], (__bf16)a[1], (__bf16)a[2], (__bf16)a[3],
              (__bf16)b[0], (__bf16)b[1], (__bf16)b[2], (__bf16)b[3]};
  return __builtin_bit_cast(u16x8, r);
}

// async global->LDS, 16B per lane; LDS dest = wave-uniform base + lane*16
__device__ __forceinline__ void gll16(const u16* g, u16* l) {
  __builtin_amdgcn_global_load_lds(
      (const __attribute__((address_space(1))) void*)g,
      (__attribute__((address_space(3))) void*)l, 16, 0, 0);
}

__device__ __forceinline__ bf16x8 ld_bf8(const u16* p) {
  return __builtin_bit_cast(bf16x8, *(const u16x8*)p);
}

__device__ __forceinline__ bf16x8 cat8(u16x4 a, u16x4 b) {
  u16x8 r = {a[0], a[1], a[2], a[3], b[0], b[1], b[2], b[3]};
  return __builtin_bit_cast(bf16x8, r);
}

__device__ __forceinline__ f32x4 mfma32(bf16x8 a, bf16x8 b, f32x4 c) {
  return __builtin_amdgcn_mfma_f32_16x16x32_bf16(a, b, c, 0, 0, 0);
}

// ---- BK=32 staged-tile swizzle (bijective; global-coalesced writes,
//      2-way-free ds_read_b128): granule g holds logical (row r, chunk c):
//      r = g>>2, c = (g&3) ^ ((g>>3)&3); read offset below.
__device__ __forceinline__ int swz_r(int g) { return g >> 2; }
__device__ __forceinline__ int swz_c(int g) { return (g & 3) ^ ((g >> 3) & 3); }
__device__ __forceinline__ int swz_off(int r, int c) {  // u16 units
  return (r * 4 + (c ^ ((r >> 1) & 3))) * 8;
}

// ------------- kernel 1: weight transpose + mask scan ---------------------
// q/k/v conversion moved INTO qkv_gemm's A-staging; memset dispatch dropped
// (mask blocks always-store flagArr[bx]; qkv block (0,0,0) OR-reduces).
__global__ __launch_bounds__(256) void pre_kernel(
    const float* __restrict__ mask, const float* __restrict__ wq,
    const float* __restrict__ wk, const float* __restrict__ wv,
    const float* __restrict__ wo, u16* __restrict__ wqT,
    u16* __restrict__ wkT, u16* __restrict__ wvT, u16* __restrict__ woT,
    int* __restrict__ flagArr) {
  int y = blockIdx.y, t = threadIdx.x;
  if (y == 0) {
    __shared__ float tile[32][33];
    int x = t & 31, yy = t >> 5;  // 32 x 8
#pragma unroll
    for (int rep = 0; rep < 2; ++rep) {
      int job = blockIdx.x * 2 + rep;
      int z = job >> 10, tt = job & 1023;
      const float* W = z == 0 ? wq : z == 1 ? wk : z == 2 ? wv : wo;
      u16* WT = z == 0 ? wqT : z == 1 ? wkT : z == 2 ? wvT : woT;
      int c0 = (tt & 31) * 32, r0 = (tt >> 5) * 32;
#pragma unroll
      for (int j = 0; j < 4; ++j)
        tile[yy + j * 8][x] = W[(u64)(r0 + yy + j * 8) * 1024 + c0 + x];
      __syncthreads();
#pragma unroll
      for (int j = 0; j < 4; ++j)
        WT[(u64)(c0 + yy + j * 8) * 1024 + r0 + x] = f2bf(tile[x][yy + j * 8]);
      __syncthreads();
    }
  } else {
    u64 i = ((u64)blockIdx.x * 256 + t) * 8;
    f32x4 a = *(const f32x4*)(mask + i);
    f32x4 b = *(const f32x4*)(mask + i + 4);
    bool nz = a[0] != 0.f || a[1] != 0.f || a[2] != 0.f || a[3] != 0.f ||
              b[0] != 0.f || b[1] != 0.f || b[2] != 0.f || b[3] != 0.f;
    int bnz = __syncthreads_or(nz ? 1 : 0);
    if (t == 0) flagArr[blockIdx.x] = bnz;  // always stored: no init needed
  }
}

// ---------------- kernel 2: fused convert + QKV projection ----------------
// A-staging is reg-staged from f32 (load f32x4 -> cvt_pk bf16 -> ds_write
// into the same swizzled layout); B stays global_load_lds from Wt. Sync is
// the verified 2-phase: vmcnt(0)+lgkmcnt(0) before EVERY barrier -> nothing
// in flight across barriers -> race-free (same argument as the R4 kernel).
// K tile layout (4096 u16 per 64-kv tile), keyed on kv bits {0,1,3}:
//   off(kv,d) = kv*64 + ((d>>3) ^ kkey(kv))*8 + (d&7),
//   kkey(kv) = (kv&3) | ((kv>>1)&4)
// V tile layout: off(kv,d) = ((kv>>2)*64 + d)*4 + (kv&3)
__global__ __launch_bounds__(256, 3) void qkv_gemm(
    const float* __restrict__ q, const float* __restrict__ k,
    const float* __restrict__ v, const u16* __restrict__ wqT,
    const u16* __restrict__ wkT, const u16* __restrict__ wvT,
    const float* __restrict__ bq, const float* __restrict__ bk,
    const float* __restrict__ bv, u16* __restrict__ Qh,
    u16* __restrict__ Khs, u16* __restrict__ Vhs,
    const int* __restrict__ flagArr, int* __restrict__ flag) {
  int z = blockIdx.z;
  const float* A = z == 0 ? q : z == 1 ? k : v;
  const u16* Wt = z == 0 ? wqT : z == 1 ? wkT : wvT;
  const float* bias = z == 0 ? bq : z == 1 ? bk : bv;
  int m0 = blockIdx.x * 128, n0 = blockIdx.y * 128;
  __shared__ __align__(16) u16 SH[18432];
  int t = threadIdx.x, w = t >> 6, lane = t & 63;
  int quad = lane >> 4, l16 = lane & 15;
  int wr = w >> 1, wc = w & 1;

  // flag OR-reduce (one block; pre completed before this kernel)
  if (z == 0 && blockIdx.x == 0 && blockIdx.y == 0) {
    int v_ = 0;
#pragma unroll
    for (int i = 0; i < 8; ++i) v_ |= flagArr[t + i * 256];
    int* sred = (int*)SH;
    sred[t] = v_;
    __syncthreads();
    if (t == 0) {
      int o = 0;
      for (int i = 0; i < 256; ++i) o |= sred[i];
      *flag = o;
    }
    __syncthreads();
  }

  f32x4 acc[4][4] = {};
  const float* ga0 = A + (u64)(m0 + swz_r(t)) * 1024 + swz_c(t) * 8;
  const float* ga1 = A + (u64)(m0 + swz_r(256 + t)) * 1024 + swz_c(256 + t) * 8;
  const u16* bg0 = Wt + (u64)(n0 + swz_r(t)) * 1024 + swz_c(t) * 8;
  const u16* bg1 = Wt + (u64)(n0 + swz_r(256 + t)) * 1024 + swz_c(256 + t) * 8;
  int aoff[4], boff[4];
#pragma unroll
  for (int i = 0; i < 4; ++i) {
    aoff[i] = swz_off(wr * 64 + i * 16 + l16, quad);
    boff[i] = 4096 + swz_off(wc * 64 + i * 16 + l16, quad);
  }
  f32x4 ar0a, ar0b, ar1a, ar1b;
#define A_ISSUE(kt)                          \
  ar0a = *(const f32x4*)(ga0 + (kt));        \
  ar0b = *(const f32x4*)(ga0 + (kt) + 4);    \
  ar1a = *(const f32x4*)(ga1 + (kt));        \
  ar1b = *(const f32x4*)(ga1 + (kt) + 4);
#define A_WRITE(buf)                                   \
  {                                                    \
    u16* D = &SH[(buf) * 8192];                        \
    *(u16x8*)&D[t * 8] = cvt8(ar0a, ar0b);             \
    *(u16x8*)&D[(256 + t) * 8] = cvt8(ar1a, ar1b);     \
  }
#define B_ISSUE(buf, kt)                                      \
  gll16(bg0 + (kt), &SH[(buf) * 8192 + 4096 + t * 8]);        \
  gll16(bg1 + (kt), &SH[(buf) * 8192 + 4096 + (256 + t) * 8]);
  // prologue: tile 0
  A_ISSUE(0);
  B_ISSUE(0, 0);
  asm volatile("s_waitcnt vmcnt(0)" ::: "memory");
  A_WRITE(0);
  asm volatile("s_waitcnt lgkmcnt(0)" ::: "memory");
  __builtin_amdgcn_s_barrier();
  __builtin_amdgcn_sched_barrier(0);
#pragma unroll
  for (int T = 0; T < 32; ++T) {
    if (T + 1 < 32) {
      A_ISSUE((T + 1) * 32);
      B_ISSUE((T + 1) & 1, (T + 1) * 32);
    }
    const u16* S = SH + (T & 1) * 8192;
    bf16x8 af[4], bfr[4];
#pragma unroll
    for (int i = 0; i < 4; ++i) af[i] = ld_bf8(&S[aoff[i]]);
#pragma unroll
    for (int i = 0; i < 4; ++i) bfr[i] = ld_bf8(&S[boff[i]]);
#pragma unroll
    for (int mi = 0; mi < 4; ++mi)
#pragma unroll
      for (int ni = 0; ni < 4; ++ni)
        acc[mi][ni] = mfma32(af[mi], bfr[ni], acc[mi][ni]);
    asm volatile("s_waitcnt vmcnt(0)" ::: "memory");
    if (T + 1 < 32) { A_WRITE((T + 1) & 1); }
    asm volatile("s_waitcnt lgkmcnt(0)" ::: "memory");
    __builtin_amdgcn_s_barrier();
    __builtin_amdgcn_sched_barrier(0);
  }
#undef A_ISSUE
#undef A_WRITE
#undef B_ISSUE

  int h = (n0 + wc * 64) >> 6;  // head, wave-uniform
  if (z == 2) {
    // V: lane's 4 r-values = one 8B half-granule, perfectly coalesced.
#pragma unroll
    for (int mi = 0; mi < 4; ++mi) {
      int gm0 = m0 + wr * 64 + mi * 16;
      int bh = (gm0 >> 11) * 16 + h;
      int tIdx = (gm0 & 2047) >> 6;
      int kvq = ((gm0 & 63) >> 2) + quad;  // kv>>2
      u16* tile = Vhs + ((u64)(bh * 32 + tIdx)) * 4096;
#pragma unroll
      for (int ni = 0; ni < 4; ++ni) {
        int d = ni * 16 + l16;
        float bv_ = bias[n0 + wc * 64 + d];
        u16x4 pv = pack4(acc[mi][ni][0] + bv_, acc[mi][ni][1] + bv_,
                         acc[mi][ni][2] + bv_, acc[mi][ni][3] + bv_);
        *(u16x4*)&tile[(kvq * 64 + d) * 4] = pv;
      }
    }
  } else {
    // Q/K: LDS transpose (rows padded to 72 u16 -> conflict-free phases),
    // then 16B granule stores (1KB contiguous per instruction).
    __syncthreads();
    u16* TB = SH + w * 2304;  // 32 rows x 72 u16 per wave
    float scale = (z == 0) ? (LOG2E / 8.f) : 1.f;
#pragma unroll
    for (int p = 0; p < 2; ++p) {
#pragma unroll
      for (int mi2 = 0; mi2 < 2; ++mi2)
#pragma unroll
        for (int ni = 0; ni < 4; ++ni) {
          int d = ni * 16 + l16;
          float bv_ = bias[n0 + wc * 64 + d];
#pragma unroll
          for (int r = 0; r < 4; ++r) {
            int kvloc = mi2 * 16 + quad * 4 + r;
            TB[kvloc * 72 + d] =
                f2bf((acc[p * 2 + mi2][ni][r] + bv_) * scale);
          }
        }
      int gm0 = m0 + wr * 64 + p * 32;
      int bh = (gm0 >> 11) * 16 + h;
#pragma unroll
      for (int i = 0; i < 4; ++i) {
        int g = i * 64 + lane;
        int kvloc = g >> 3, slot = g & 7;
        if (z == 0) {
          u16x8 gran = *(u16x8*)&TB[kvloc * 72 + slot * 8];
          int s = (gm0 & 2047) + kvloc;
          *(u16x8*)&Qh[((u64)bh * 2048 + s) * 64 + slot * 8] = gran;
        } else {
          int kk = (kvloc & 3) | ((kvloc >> 1) & 4);  // kkey(kv), bits {0,1,3}
          u16x8 gran = *(u16x8*)&TB[kvloc * 72 + (slot ^ kk) * 8];
          int tIdx = (gm0 & 2047) >> 6;
          int kv = (gm0 & 63) + kvloc;
          *(u16x8*)&Khs[((u64)(bh * 32 + tIdx)) * 4096 + kv * 64 + slot * 8] =
              gran;
        }
      }
    }
  }
}

// ---------------- kernel 3: flash attention (128q blocks, R5) -------------
// 128 q-rows x one bh per block; 8 waves = 8 q-strips of 16 rows, each wave
// consumes the FULL 64-kv tile. PV runs on 16x16x32 MFMA: QK chunk cc loads
// K rows kvr = (cc>>1)*32 + (l16>>2)*8 + (cc&1)*4 + (l16&3), so the S
// fragment pair [pk[2g], pk[2g+1]] is exactly the x32 A-operand
// (kv = g*32 + quad*8 + 0..7) -- no shuffles. kkey makes x7 = l16&7 still.
// NOTE (R6 lesson): splitting to 64q/4-wave blocks REGRESSED (47.3 vs 44.8);
// flash's limiter is the per-step serial chain, not wave-count.
template <int CUR>
__device__ __forceinline__ void fa_fast_step(
    int T, int t, int quad, int l16, int x7,
    const u16* __restrict__ Kg0, const u16* __restrict__ Vg0, u16* Kb0,
    u16* Vb0, bf16x8 aq0, bf16x8 aq1, f32x4 (&o)[4], f32x4& l_acc,
    bf16x8 ones8) {
  if (T + 1 < 32) {
    gll16(Kg0 + (u64)(T + 1) * 4096 + t * 8, &Kb0[(CUR ^ 1) * 4096 + t * 8]);
    gll16(Vg0 + (u64)(T + 1) * 4096 + t * 8, &Vb0[(CUR ^ 1) * 4096 + t * 8]);
  }
  const u16* Kt = Kb0 + CUR * 4096;
  const u16* Vt = Vb0 + CUR * 4096;
  int lbase = (l16 >> 2) * 8 + (l16 & 3);
  u16x4 pk[4];
#pragma unroll
  for (int cc = 0; cc < 4; ++cc) {
    int kvr = (cc >> 1) * 32 + (cc & 1) * 4 + lbase;
    bf16x8 k0 = ld_bf8(&Kt[kvr * 64 + ((quad ^ x7)) * 8]);
    bf16x8 k1 = ld_bf8(&Kt[kvr * 64 + (((quad + 4) ^ x7)) * 8]);
    f32x4 s_ = {};
    s_ = mfma32(k0, aq0, s_);
    s_ = mfma32(k1, aq1, s_);
    pk[cc] = pack4(ex2(s_[0]), ex2(s_[1]), ex2(s_[2]), ex2(s_[3]));
  }
  __builtin_amdgcn_s_setprio(1);
#pragma unroll
  for (int g = 0; g < 2; ++g) {
    bf16x8 pa = cat8(pk[g * 2], pk[g * 2 + 1]);
    l_acc = mfma32(pa, ones8, l_acc);
#pragma unroll
    for (int nt = 0; nt < 4; ++nt) {
      const u16* vb = &Vt[(((g * 8 + quad * 2) * 64) + nt * 16 + l16) * 4];
      bf16x8 vf = cat8(*(const u16x4*)vb, *(const u16x4*)(vb + 256));
      o[nt] = mfma32(pa, vf, o[nt]);
    }
  }
  __builtin_amdgcn_s_setprio(0);
  __syncthreads();
}

template <int CUR>
__device__ __forceinline__ void fa_mask_step(
    int T, int t, int lane, int quad, int l16, int x7, int qg,
    const u16* __restrict__ Kg0, const u16* __restrict__ Vg0,
    const float* __restrict__ mask, u16* Kb0, u16* Vb0, bf16x8 aq0,
    bf16x8 aq1, f32x4 (&o)[4], float& m_r, float& l_r) {
  if (T + 1 < 32) {
    gll16(Kg0 + (u64)(T + 1) * 4096 + t * 8, &Kb0[(CUR ^ 1) * 4096 + t * 8]);
    gll16(Vg0 + (u64)(T + 1) * 4096 + t * 8, &Vb0[(CUR ^ 1) * 4096 + t * 8]);
  }
  const u16* Kt = Kb0 + CUR * 4096;
  const u16* Vt = Vb0 + CUR * 4096;
  int lbase = (l16 >> 2) * 8 + (l16 & 3);
  f32x4 sv[4];
#pragma unroll
  for (int cc = 0; cc < 4; ++cc) {
    int kvr = (cc >> 1) * 32 + (cc & 1) * 4 + lbase;
    bf16x8 k0 = ld_bf8(&Kt[kvr * 64 + ((quad ^ x7)) * 8]);
    bf16x8 k1 = ld_bf8(&Kt[kvr * 64 + (((quad + 4) ^ x7)) * 8]);
    f32x4 s_ = {};
    s_ = mfma32(k0, aq0, s_);
    s_ = mfma32(k1, aq1, s_);
    sv[cc] = s_;
  }
  // D-row quad*4+r of chunk cc holds kv = (cc>>1)*32 + quad*8 + (cc&1)*4 + r
#pragma unroll
  for (int cc = 0; cc < 4; ++cc)
#pragma unroll
    for (int r = 0; r < 4; ++r)
      sv[cc][r] += mask[(u64)qg * 2048 + T * 64 + (cc >> 1) * 32 + quad * 8 +
                        (cc & 1) * 4 + r] *
                   (-1e9f * LOG2E);
  float mx = -1e30f;
#pragma unroll
  for (int cc = 0; cc < 4; ++cc)
    mx = fmaxf(mx, fmaxf(fmaxf(sv[cc][0], sv[cc][1]),
                         fmaxf(sv[cc][2], sv[cc][3])));
  mx = fmaxf(mx, __shfl_xor(mx, 16));
  mx = fmaxf(mx, __shfl_xor(mx, 32));
  float mnew = fmaxf(m_r, mx);
  float alpha = ex2(m_r - mnew);
  m_r = mnew;
  float rs = 0.f;
  u16x4 pk[4];
#pragma unroll
  for (int cc = 0; cc < 4; ++cc) {
    float p0 = ex2(sv[cc][0] - m_r), p1 = ex2(sv[cc][1] - m_r);
    float p2 = ex2(sv[cc][2] - m_r), p3 = ex2(sv[cc][3] - m_r);
    rs += (p0 + p1) + (p2 + p3);
    pk[cc] = pack4(p0, p1, p2, p3);
  }
  rs += __shfl_xor(rs, 16);
  rs += __shfl_xor(rs, 32);
  l_r = l_r * alpha + rs;
  float a4[4];
#pragma unroll
  for (int r = 0; r < 4; ++r)
    a4[r] = __shfl(alpha, (lane & 48) | (quad * 4 + r));
#pragma unroll
  for (int nt = 0; nt < 4; ++nt)
#pragma unroll
    for (int r = 0; r < 4; ++r) o[nt][r] *= a4[r];
  __builtin_amdgcn_s_setprio(1);
#pragma unroll
  for (int g = 0; g < 2; ++g) {
    bf16x8 pa = cat8(pk[g * 2], pk[g * 2 + 1]);
#pragma unroll
    for (int nt = 0; nt < 4; ++nt) {
      const u16* vb = &Vt[(((g * 8 + quad * 2) * 64) + nt * 16 + l16) * 4];
      bf16x8 vf = cat8(*(const u16x4*)vb, *(const u16x4*)(vb + 256));
      o[nt] = mfma32(pa, vf, o[nt]);
    }
  }
  __builtin_amdgcn_s_setprio(0);
  __syncthreads();
}

__global__ __launch_bounds__(512, 4) void flash_attn(
    const u16* __restrict__ Qh, const u16* __restrict__ Khs,
    const u16* __restrict__ Vhs, const float* __restrict__ mask,
    const int* __restrict__ flag, u16* __restrict__ Ob) {
  int L = blockIdx.x + (blockIdx.y << 4);   // grid (16,32): L in [0,512)
  int bh = (L & 7) * 4 + ((L >> 3) & 3);    // XCD-confined bh group
  int q0 = (L >> 5) * 128;
  int t = threadIdx.x, w = t >> 6, lane = t & 63;
  int quad = lane >> 4, l16 = lane & 15;
  __shared__ u16 SMEM[16384];  // Kb[2][4096] | Vb[2][4096] = 32 KB
  u16* Kb0 = SMEM;
  u16* Vb0 = SMEM + 8192;
  const u16* Kg0 = Khs + (u64)bh * 32 * 4096;
  const u16* Vg0 = Vhs + (u64)bh * 32 * 4096;
  const u16* Qbase = Qh + ((u64)bh * 2048 + q0 + w * 16 + l16) * 64 + quad * 8;
  bf16x8 aq0 = ld_bf8(Qbase);
  bf16x8 aq1 = ld_bf8(Qbase + 32);
  f32x4 o[4] = {};
  const bool use_mask = (*flag) != 0;
  int x7 = l16 & 7;
  const u16x8 ones8u = {0x3F80, 0x3F80, 0x3F80, 0x3F80,
                        0x3F80, 0x3F80, 0x3F80, 0x3F80};
  bf16x8 ones8 = __builtin_bit_cast(bf16x8, ones8u);
  // stage tile 0: one K + one V granule per thread
  gll16(Kg0 + t * 8, &Kb0[t * 8]);
  gll16(Vg0 + t * 8, &Vb0[t * 8]);
  __syncthreads();
  int b = bh >> 4, h = bh & 15;
  if (!use_mask) {
    f32x4 l_acc = {};
    for (int T = 0; T < 32; T += 2) {
      fa_fast_step<0>(T, t, quad, l16, x7, Kg0, Vg0, Kb0, Vb0, aq0, aq1, o,
                      l_acc, ones8);
      fa_fast_step<1>(T + 1, t, quad, l16, x7, Kg0, Vg0, Kb0, Vb0, aq0, aq1,
                      o, l_acc, ones8);
    }
    float rl[4];
#pragma unroll
    for (int r = 0; r < 4; ++r) rl[r] = 1.f / l_acc[r];
#pragma unroll
    for (int nt = 0; nt < 4; ++nt)
#pragma unroll
      for (int r = 0; r < 4; ++r) {
        int srow = q0 + w * 16 + quad * 4 + r;
        Ob[(u64)(b * 2048 + srow) * 1024 + h * 64 + nt * 16 + l16] =
            f2bf(o[nt][r] * rl[r]);
      }
  } else {
    float m_r = -1e30f, l_r = 0.f;  // per-lane softmax state for q = l16
    int qg = q0 + w * 16 + l16;
    for (int T = 0; T < 32; T += 2) {
      fa_mask_step<0>(T, t, lane, quad, l16, x7, qg, Kg0, Vg0, mask, Kb0, Vb0,
                      aq0, aq1, o, m_r, l_r);
      fa_mask_step<1>(T + 1, t, lane, quad, l16, x7, qg, Kg0, Vg0, mask, Kb0,
                      Vb0, aq0, aq1, o, m_r, l_r);
    }
    float rl[4];
#pragma unroll
    for (int r = 0; r < 4; ++r)
      rl[r] = 1.f / __shfl(l_r, (lane & 48) | (quad * 4 + r));
#pragma unroll
    for (int nt = 0; nt < 4; ++nt)
#pragma unroll
      for (int r = 0; r < 4; ++r) {
        int srow = q0 + w * 16 + quad * 4 + r;
        Ob[(u64)(b * 2048 + srow) * 1024 + h * 64 + nt * 16 + l16] =
            f2bf(o[nt][r] * rl[r]);
      }
  }
}

// ---------------- kernel 4: output projection (BK=64, 2-phase) ------------
__global__ __launch_bounds__(256, 2) void out_gemm(const u16* __restrict__ Ob,
                                                   const u16* __restrict__ woT,
                                                   const float* __restrict__ bo,
                                                   float* __restrict__ out) {
  int m0 = blockIdx.x * 128, n0 = blockIdx.y * 64;
  __shared__ __align__(16) u16 SH[24576];  // 2 stages x (A 8192 + B 4096)
  f32x4 acc[2][4] = {};
  int t = threadIdx.x, w = t >> 6, lane = t & 63;
  int quad = lane >> 4, l16 = lane & 15;
  const u16* ag[4];
  const u16* bgp[2];
#pragma unroll
  for (int j = 0; j < 4; ++j) {
    int g = j * 256 + t, row = g >> 3, cc = (g & 7) ^ (row & 7);
    ag[j] = Ob + (u64)(m0 + row) * 1024 + cc * 8;
  }
#pragma unroll
  for (int j = 0; j < 2; ++j) {
    int g = j * 256 + t, row = g >> 3, cc = (g & 7) ^ (row & 7);
    bgp[j] = woT + (u64)(n0 + row) * 1024 + cc * 8;
  }
#define OSTAGE(buf, kt)                                              \
  {                                                                  \
    u16* D = &SH[(buf) * 12288];                                     \
    gll16(ag[0] + (kt), &D[t * 8]);                                  \
    gll16(ag[1] + (kt), &D[(256 + t) * 8]);                          \
    gll16(ag[2] + (kt), &D[(512 + t) * 8]);                          \
    gll16(ag[3] + (kt), &D[(768 + t) * 8]);                          \
    gll16(bgp[0] + (kt), &D[8192 + t * 8]);                          \
    gll16(bgp[1] + (kt), &D[8192 + (256 + t) * 8]);                  \
  }
  OSTAGE(0, 0);
  asm volatile("s_waitcnt vmcnt(0)" ::: "memory");
  __builtin_amdgcn_s_barrier();
  __builtin_amdgcn_sched_barrier(0);
#pragma unroll
  for (int T = 0; T < 16; ++T) {
    if (T + 1 < 16) { OSTAGE((T + 1) & 1, (T + 1) * 64); }
    const u16* S = SH + (T & 1) * 12288;
#pragma unroll
    for (int ks = 0; ks < 2; ++ks) {
      bf16x8 af[2], bfr[4];
#pragma unroll
      for (int i = 0; i < 2; ++i) {
        int r = w * 32 + i * 16 + l16;
        af[i] = ld_bf8(&S[(r * 8 + ((ks * 4 + quad) ^ (r & 7))) * 8]);
      }
#pragma unroll
      for (int i = 0; i < 4; ++i) {
        int r = i * 16 + l16;
        bfr[i] = ld_bf8(&S[8192 + (r * 8 + ((ks * 4 + quad) ^ (r & 7))) * 8]);
      }
#pragma unroll
      for (int mi = 0; mi < 2; ++mi)
#pragma unroll
        for (int ni = 0; ni < 4; ++ni)
          acc[mi][ni] = mfma32(af[mi], bfr[ni], acc[mi][ni]);
    }
    asm volatile("s_waitcnt vmcnt(0)" ::: "memory");
    __builtin_amdgcn_s_barrier();
    __builtin_amdgcn_sched_barrier(0);
  }
#undef OSTAGE
#pragma unroll
  for (int mi = 0; mi < 2; ++mi) {
#pragma unroll
    for (int ni = 0; ni < 4; ++ni) {
      int gn = n0 + ni * 16 + l16;
      float bv_ = bo[gn];
#pragma unroll
      for (int r = 0; r < 4; ++r) {
        int gm = m0 + w * 32 + mi * 16 + quad * 4 + r;
        out[(u64)gm * 1024 + gn] = acc[mi][ni][r] + bv_;
      }
    }
  }
}

extern "C" void kernel_launch(void* const* d_in, const int* in_sizes, int n_in,
                              void* d_out, int out_size, void* d_ws,
                              size_t ws_size, hipStream_t stream) {
  const float* q = (const float*)d_in[0];
  const float* k = (const float*)d_in[1];
  const float* v = (const float*)d_in[2];
  const float* mask = (const float*)d_in[3];
  const float* wq = (const float*)d_in[4];
  const float* bq = (const float*)d_in[5];
  const float* wk = (const float*)d_in[6];
  const float* bk = (const float*)d_in[7];
  const float* wv = (const float*)d_in[8];
  const float* bv = (const float*)d_in[9];
  const float* wo = (const float*)d_in[10];
  const float* bo = (const float*)d_in[11];
  float* out = (float*)d_out;
  char* ws = (char*)d_ws;
  const u64 MB = 1ull << 20;
  u16* Ob = (u16*)(ws + 0 * MB);    // attn output (8 MB)
  u16* wqT = (u16*)(ws + 24 * MB);
  u16* wkT = (u16*)(ws + 26 * MB);
  u16* wvT = (u16*)(ws + 28 * MB);
  u16* woT = (u16*)(ws + 30 * MB);
  u16* Qh = (u16*)(ws + 32 * MB);   // [32 bh][2048][64] bf16
  u16* Khs = (u16*)(ws + 40 * MB);  // [32 bh][32 tiles][4096] kkey-xor
  u16* Vhs = (u16*)(ws + 48 * MB);  // [32 bh][32 tiles][4096] 4kv-interleave
  int* flag = (int*)(ws + 56 * MB);
  int* flagArr = (int*)(ws + 56 * MB + 4096);  // 2048 ints, always stored

  pre_kernel<<<dim3(2048, 2), 256, 0, stream>>>(
      mask, wq, wk, wv, wo, wqT, wkT, wvT, woT, flagArr);
  qkv_gemm<<<dim3(32, 8, 3), 256, 0, stream>>>(q, k, v, wqT, wkT, wvT, bq, bk,
                                               bv, Qh, Khs, Vhs, flagArr, flag);
  flash_attn<<<dim3(16, 32), 512, 0, stream>>>(Qh, Khs, Vhs, mask, flag, Ob);
  out_gemm<<<dim3(32, 16), 256, 0, stream>>>(Ob, woT, bo, out);
}

// Round 9
// 218.722 us; speedup vs baseline: 1.1648x; 1.1648x over previous
//
#include <hip/hip_runtime.h>

typedef unsigned short u16;
typedef unsigned int   u32;
typedef unsigned long long u64;
typedef short s16;

using f32x4  = __attribute__((ext_vector_type(4))) float;
using bf16x8 = __attribute__((ext_vector_type(8))) __bf16;
using bf16x4 = __attribute__((ext_vector_type(4))) __bf16;
using u16x8  = __attribute__((ext_vector_type(8))) u16;
using u16x4  = __attribute__((ext_vector_type(4))) u16;
using s16x4  = __attribute__((ext_vector_type(4))) s16;

#define LOG2E 1.4426950408889634f

// float -> bf16 with round-to-nearest-even (cold paths)
__device__ __forceinline__ u16 f2bf(float f) {
  u32 u = __builtin_bit_cast(u32, f);
  u32 r = u + 0x7fffu + ((u >> 16) & 1u);
  return (u16)(r >> 16);
}

// raw v_exp_f32 (OCML exp2f carries denormal fixup = ~10 VALU per call)
__device__ __forceinline__ float ex2(float x) {
#if __has_builtin(__builtin_amdgcn_exp2f)
  return __builtin_amdgcn_exp2f(x);
#else
  return exp2f(x);
#endif
}

// native __bf16 casts: compiler emits v_cvt_pk_bf16_f32 pairs
__device__ __forceinline__ u16x4 pack4(float p0, float p1, float p2, float p3) {
  bf16x4 b = {(__bf16)p0, (__bf16)p1, (__bf16)p2, (__bf16)p3};
  return __builtin_bit_cast(u16x4, b);
}

// async global->LDS, 16B per lane; LDS dest = wave-uniform base + lane*16
__device__ __forceinline__ void gll16(const u16* g, u16* l) {
  __builtin_amdgcn_global_load_lds(
      (const __attribute__((address_space(1))) void*)g,
      (__attribute__((address_space(3))) void*)l, 16, 0, 0);
}

__device__ __forceinline__ bf16x8 ld_bf8(const u16* p) {
  return __builtin_bit_cast(bf16x8, *(const u16x8*)p);
}

__device__ __forceinline__ bf16x8 cat8(u16x4 a, u16x4 b) {
  u16x8 r = {a[0], a[1], a[2], a[3], b[0], b[1], b[2], b[3]};
  return __builtin_bit_cast(bf16x8, r);
}

__device__ __forceinline__ f32x4 mfma32(bf16x8 a, bf16x8 b, f32x4 c) {
  return __builtin_amdgcn_mfma_f32_16x16x32_bf16(a, b, c, 0, 0, 0);
}

// ---- BK=32 staged-tile swizzle (bijective; global-coalesced writes,
//      2-way-free ds_read_b128): granule g holds logical (row r, chunk c):
//      r = g>>2, c = (g&3) ^ ((g>>3)&3); read offset below.
__device__ __forceinline__ int swz_r(int g) { return g >> 2; }
__device__ __forceinline__ int swz_c(int g) { return (g & 3) ^ ((g >> 3) & 3); }
__device__ __forceinline__ int swz_off(int r, int c) {  // u16 units
  return (r * 4 + (c ^ ((r >> 1) & 3))) * 8;
}

// ------------- kernel 1: fused convert + weight transpose + mask scan -----
// R8 lesson: the q/k/v f32->bf16 convert MUST stay here (BW-bound streaming
// at full TLP, and it leaves qb/kb/vb L2/L3-warm for qkv_gemm). Fusing it
// into qkv's staging regressed 45->90 us (cold-HBM latency under a short
// compute phase). Mask scan always-stores flagArr (no memset needed).
__global__ __launch_bounds__(256) void pre_kernel(
    const float* __restrict__ q, const float* __restrict__ k,
    const float* __restrict__ v, const float* __restrict__ mask,
    const float* __restrict__ wq, const float* __restrict__ wk,
    const float* __restrict__ wv, const float* __restrict__ wo,
    u16* __restrict__ qb, u16* __restrict__ kb, u16* __restrict__ vb,
    u16* __restrict__ wqT, u16* __restrict__ wkT, u16* __restrict__ wvT,
    u16* __restrict__ woT, int* __restrict__ flagArr) {
  int y = blockIdx.y, t = threadIdx.x;
  if (y < 3) {
    const float* src = y == 0 ? q : y == 1 ? k : v;
    u16* dst = y == 0 ? qb : y == 1 ? kb : vb;
    u64 i = ((u64)blockIdx.x * 256 + t) * 8;
    f32x4 a = *(const f32x4*)(src + i);
    f32x4 b = *(const f32x4*)(src + i + 4);
    u16x8 o;
    o[0] = f2bf(a[0]); o[1] = f2bf(a[1]); o[2] = f2bf(a[2]); o[3] = f2bf(a[3]);
    o[4] = f2bf(b[0]); o[5] = f2bf(b[1]); o[6] = f2bf(b[2]); o[7] = f2bf(b[3]);
    *(u16x8*)(dst + i) = o;
  } else if (y == 3) {
    __shared__ float tile[32][33];
    int x = t & 31, yy = t >> 5;  // 32 x 8
#pragma unroll
    for (int rep = 0; rep < 2; ++rep) {
      int job = blockIdx.x * 2 + rep;
      int z = job >> 10, tt = job & 1023;
      const float* W = z == 0 ? wq : z == 1 ? wk : z == 2 ? wv : wo;
      u16* WT = z == 0 ? wqT : z == 1 ? wkT : z == 2 ? wvT : woT;
      int c0 = (tt & 31) * 32, r0 = (tt >> 5) * 32;
#pragma unroll
      for (int j = 0; j < 4; ++j)
        tile[yy + j * 8][x] = W[(u64)(r0 + yy + j * 8) * 1024 + c0 + x];
      __syncthreads();
#pragma unroll
      for (int j = 0; j < 4; ++j)
        WT[(u64)(c0 + yy + j * 8) * 1024 + r0 + x] = f2bf(tile[x][yy + j * 8]);
      __syncthreads();
    }
  } else {
    u64 i = ((u64)blockIdx.x * 256 + t) * 8;
    f32x4 a = *(const f32x4*)(mask + i);
    f32x4 b = *(const f32x4*)(mask + i + 4);
    bool nz = a[0] != 0.f || a[1] != 0.f || a[2] != 0.f || a[3] != 0.f ||
              b[0] != 0.f || b[1] != 0.f || b[2] != 0.f || b[3] != 0.f;
    int bnz = __syncthreads_or(nz ? 1 : 0);
    if (t == 0) flagArr[blockIdx.x] = bnz;  // always stored: no init needed
  }
}

// ---------------- shared GEMM core (BK=32, 2-phase overlap) ---------------
// T3 minimum recipe (m248v2-verified): issue STAGE(t+1) BEFORE compute(t),
// then vmcnt(0)+barrier once per K-step. vmcnt fully drained before every
// barrier -> no writes in flight across barriers -> race-free (the R3
// counted-vmcnt schedule tripwired). Loads for t+1 fly during compute(t).
__device__ __forceinline__ void gemm_core(const u16* __restrict__ A,
                                          const u16* __restrict__ Wt, int m0,
                                          int n0, u16* SH, f32x4 acc[4][4]) {
  int t = threadIdx.x, w = t >> 6, lane = t & 63;
  int quad = lane >> 4, l16 = lane & 15;
  int wr = w >> 1, wc = w & 1;
  const u16* a0 = A + (u64)(m0 + swz_r(t)) * 1024 + swz_c(t) * 8;
  const u16* a1 = A + (u64)(m0 + swz_r(256 + t)) * 1024 + swz_c(256 + t) * 8;
  const u16* bg0 = Wt + (u64)(n0 + swz_r(t)) * 1024 + swz_c(t) * 8;
  const u16* bg1 = Wt + (u64)(n0 + swz_r(256 + t)) * 1024 + swz_c(256 + t) * 8;
  int aoff[4], boff[4];
#pragma unroll
  for (int i = 0; i < 4; ++i) {
    aoff[i] = swz_off(wr * 64 + i * 16 + l16, quad);
    boff[i] = 4096 + swz_off(wc * 64 + i * 16 + l16, quad);
  }
#define QSTAGE(buf, kt)                                         \
  gll16(a0 + (kt), &SH[(buf) * 8192 + t * 8]);                  \
  gll16(bg0 + (kt), &SH[(buf) * 8192 + 4096 + t * 8]);          \
  gll16(a1 + (kt), &SH[(buf) * 8192 + (256 + t) * 8]);          \
  gll16(bg1 + (kt), &SH[(buf) * 8192 + 4096 + (256 + t) * 8]);
  QSTAGE(0, 0);
  asm volatile("s_waitcnt vmcnt(0)" ::: "memory");
  __builtin_amdgcn_s_barrier();
  __builtin_amdgcn_sched_barrier(0);
#pragma unroll
  for (int T = 0; T < 32; ++T) {
    if (T + 1 < 32) { QSTAGE((T + 1) & 1, (T + 1) * 32); }
    const u16* S = SH + (T & 1) * 8192;
    bf16x8 af[4], bfr[4];
#pragma unroll
    for (int i = 0; i < 4; ++i) af[i] = ld_bf8(&S[aoff[i]]);
#pragma unroll
    for (int i = 0; i < 4; ++i) bfr[i] = ld_bf8(&S[boff[i]]);
#pragma unroll
    for (int mi = 0; mi < 4; ++mi)
#pragma unroll
      for (int ni = 0; ni < 4; ++ni)
        acc[mi][ni] = mfma32(af[mi], bfr[ni], acc[mi][ni]);
    asm volatile("s_waitcnt vmcnt(0)" ::: "memory");
    __builtin_amdgcn_s_barrier();
    __builtin_amdgcn_sched_barrier(0);
  }
#undef QSTAGE
}

// ---------------- kernel 2: fused QKV projection --------------------------
// K tile layout (4096 u16 per 64-kv tile), keyed on kv bits {0,1,3} so the
// PV-x32 row permutation in flash keeps the 8-slot bank spread:
//   off(kv,d) = kv*64 + ((d>>3) ^ kkey(kv))*8 + (d&7),
//   kkey(kv) = (kv&3) | ((kv>>1)&4)
// V tile layout: off(kv,d) = ((kv>>2)*64 + d)*4 + (kv&3)
__global__ __launch_bounds__(256, 3) void qkv_gemm(
    const u16* __restrict__ qb, const u16* __restrict__ kb,
    const u16* __restrict__ vb, const u16* __restrict__ wqT,
    const u16* __restrict__ wkT, const u16* __restrict__ wvT,
    const float* __restrict__ bq, const float* __restrict__ bk,
    const float* __restrict__ bv, u16* __restrict__ Qh,
    u16* __restrict__ Khs, u16* __restrict__ Vhs,
    const int* __restrict__ flagArr, int* __restrict__ flag) {
  int z = blockIdx.z;
  const u16* A = z == 0 ? qb : z == 1 ? kb : vb;
  const u16* Wt = z == 0 ? wqT : z == 1 ? wkT : wvT;
  const float* bias = z == 0 ? bq : z == 1 ? bk : bv;
  int m0 = blockIdx.x * 128, n0 = blockIdx.y * 128;
  // 2 stage-buffers (2 x 8192 u16 = 32 KB) + headroom for the 18432-u16
  // transpose scratch reused by the epilogue.
  __shared__ __align__(16) u16 SH[18432];
  int t = threadIdx.x, w = t >> 6, lane = t & 63;
  int quad = lane >> 4, l16 = lane & 15;
  int wr = w >> 1, wc = w & 1;

  // flag OR-reduce (one block; pre completed before this kernel) [R8-verified]
  if (z == 0 && blockIdx.x == 0 && blockIdx.y == 0) {
    int v_ = 0;
#pragma unroll
    for (int i = 0; i < 8; ++i) v_ |= flagArr[t + i * 256];
    int* sred = (int*)SH;
    sred[t] = v_;
    __syncthreads();
    if (t == 0) {
      int o = 0;
      for (int i = 0; i < 256; ++i) o |= sred[i];
      *flag = o;
    }
    __syncthreads();
  }

  f32x4 acc[4][4] = {};
  gemm_core(A, Wt, m0, n0, SH, acc);
  int h = (n0 + wc * 64) >> 6;  // head, wave-uniform
  if (z == 2) {
    // V: lane's 4 r-values = one 8B half-granule, perfectly coalesced.
#pragma unroll
    for (int mi = 0; mi < 4; ++mi) {
      int gm0 = m0 + wr * 64 + mi * 16;
      int bh = (gm0 >> 11) * 16 + h;
      int tIdx = (gm0 & 2047) >> 6;
      int kvq = ((gm0 & 63) >> 2) + quad;  // kv>>2
      u16* tile = Vhs + ((u64)(bh * 32 + tIdx)) * 4096;
#pragma unroll
      for (int ni = 0; ni < 4; ++ni) {
        int d = ni * 16 + l16;
        float bv_ = bias[n0 + wc * 64 + d];
        u16x4 pv = pack4(acc[mi][ni][0] + bv_, acc[mi][ni][1] + bv_,
                         acc[mi][ni][2] + bv_, acc[mi][ni][3] + bv_);
        *(u16x4*)&tile[(kvq * 64 + d) * 4] = pv;
      }
    }
  } else {
    // Q/K: LDS transpose (rows padded to 72 u16 -> conflict-free phases),
    // then 16B granule stores (1KB contiguous per instruction).
    __syncthreads();
    u16* TB = SH + w * 2304;  // 32 rows x 72 u16 per wave
    float scale = (z == 0) ? (LOG2E / 8.f) : 1.f;
#pragma unroll
    for (int p = 0; p < 2; ++p) {
#pragma unroll
      for (int mi2 = 0; mi2 < 2; ++mi2)
#pragma unroll
        for (int ni = 0; ni < 4; ++ni) {
          int d = ni * 16 + l16;
          float bv_ = bias[n0 + wc * 64 + d];
#pragma unroll
          for (int r = 0; r < 4; ++r) {
            int kvloc = mi2 * 16 + quad * 4 + r;
            TB[kvloc * 72 + d] =
                f2bf((acc[p * 2 + mi2][ni][r] + bv_) * scale);
          }
        }
      int gm0 = m0 + wr * 64 + p * 32;
      int bh = (gm0 >> 11) * 16 + h;
#pragma unroll
      for (int i = 0; i < 4; ++i) {
        int g = i * 64 + lane;
        int kvloc = g >> 3, slot = g & 7;
        if (z == 0) {
          u16x8 gran = *(u16x8*)&TB[kvloc * 72 + slot * 8];
          int s = (gm0 & 2047) + kvloc;
          *(u16x8*)&Qh[((u64)bh * 2048 + s) * 64 + slot * 8] = gran;
        } else {
          int kk = (kvloc & 3) | ((kvloc >> 1) & 4);  // kkey(kv), bits {0,1,3}
          u16x8 gran = *(u16x8*)&TB[kvloc * 72 + (slot ^ kk) * 8];
          int tIdx = (gm0 & 2047) >> 6;
          int kv = (gm0 & 63) + kvloc;
          *(u16x8*)&Khs[((u64)(bh * 32 + tIdx)) * 4096 + kv * 64 + slot * 8] =
              gran;
        }
      }
    }
  }
}

// ---------------- kernel 3: flash attention (128q blocks, R5) -------------
// 128 q-rows x one bh per block; 8 waves = 8 q-strips of 16 rows, each wave
// consumes the FULL 64-kv tile. PV runs on 16x16x32 MFMA: QK chunk cc loads
// K rows kvr = (cc>>1)*32 + (l16>>2)*8 + (cc&1)*4 + (l16&3), so the S
// fragment pair [pk[2g], pk[2g+1]] is exactly the x32 A-operand
// (kv = g*32 + quad*8 + 0..7) -- no shuffles. kkey makes x7 = l16&7 still.
// NOTE (R6 lesson): splitting to 64q/4-wave blocks REGRESSED (47.3 vs 44.8);
// flash's limiter is the per-step serial chain, not wave-count.
template <int CUR>
__device__ __forceinline__ void fa_fast_step(
    int T, int t, int quad, int l16, int x7,
    const u16* __restrict__ Kg0, const u16* __restrict__ Vg0, u16* Kb0,
    u16* Vb0, bf16x8 aq0, bf16x8 aq1, f32x4 (&o)[4], f32x4& l_acc,
    bf16x8 ones8) {
  if (T + 1 < 32) {
    gll16(Kg0 + (u64)(T + 1) * 4096 + t * 8, &Kb0[(CUR ^ 1) * 4096 + t * 8]);
    gll16(Vg0 + (u64)(T + 1) * 4096 + t * 8, &Vb0[(CUR ^ 1) * 4096 + t * 8]);
  }
  const u16* Kt = Kb0 + CUR * 4096;
  const u16* Vt = Vb0 + CUR * 4096;
  int lbase = (l16 >> 2) * 8 + (l16 & 3);
  u16x4 pk[4];
#pragma unroll
  for (int cc = 0; cc < 4; ++cc) {
    int kvr = (cc >> 1) * 32 + (cc & 1) * 4 + lbase;
    bf16x8 k0 = ld_bf8(&Kt[kvr * 64 + ((quad ^ x7)) * 8]);
    bf16x8 k1 = ld_bf8(&Kt[kvr * 64 + (((quad + 4) ^ x7)) * 8]);
    f32x4 s_ = {};
    s_ = mfma32(k0, aq0, s_);
    s_ = mfma32(k1, aq1, s_);
    pk[cc] = pack4(ex2(s_[0]), ex2(s_[1]), ex2(s_[2]), ex2(s_[3]));
  }
  __builtin_amdgcn_s_setprio(1);
#pragma unroll
  for (int g = 0; g < 2; ++g) {
    bf16x8 pa = cat8(pk[g * 2], pk[g * 2 + 1]);
    l_acc = mfma32(pa, ones8, l_acc);
#pragma unroll
    for (int nt = 0; nt < 4; ++nt) {
      const u16* vb = &Vt[(((g * 8 + quad * 2) * 64) + nt * 16 + l16) * 4];
      bf16x8 vf = cat8(*(const u16x4*)vb, *(const u16x4*)(vb + 256));
      o[nt] = mfma32(pa, vf, o[nt]);
    }
  }
  __builtin_amdgcn_s_setprio(0);
  __syncthreads();
}

template <int CUR>
__device__ __forceinline__ void fa_mask_step(
    int T, int t, int lane, int quad, int l16, int x7, int qg,
    const u16* __restrict__ Kg0, const u16* __restrict__ Vg0,
    const float* __restrict__ mask, u16* Kb0, u16* Vb0, bf16x8 aq0,
    bf16x8 aq1, f32x4 (&o)[4], float& m_r, float& l_r) {
  if (T + 1 < 32) {
    gll16(Kg0 + (u64)(T + 1) * 4096 + t * 8, &Kb0[(CUR ^ 1) * 4096 + t * 8]);
    gll16(Vg0 + (u64)(T + 1) * 4096 + t * 8, &Vb0[(CUR ^ 1) * 4096 + t * 8]);
  }
  const u16* Kt = Kb0 + CUR * 4096;
  const u16* Vt = Vb0 + CUR * 4096;
  int lbase = (l16 >> 2) * 8 + (l16 & 3);
  f32x4 sv[4];
#pragma unroll
  for (int cc = 0; cc < 4; ++cc) {
    int kvr = (cc >> 1) * 32 + (cc & 1) * 4 + lbase;
    bf16x8 k0 = ld_bf8(&Kt[kvr * 64 + ((quad ^ x7)) * 8]);
    bf16x8 k1 = ld_bf8(&Kt[kvr * 64 + (((quad + 4) ^ x7)) * 8]);
    f32x4 s_ = {};
    s_ = mfma32(k0, aq0, s_);
    s_ = mfma32(k1, aq1, s_);
    sv[cc] = s_;
  }
  // D-row quad*4+r of chunk cc holds kv = (cc>>1)*32 + quad*8 + (cc&1)*4 + r
#pragma unroll
  for (int cc = 0; cc < 4; ++cc)
#pragma unroll
    for (int r = 0; r < 4; ++r)
      sv[cc][r] += mask[(u64)qg * 2048 + T * 64 + (cc >> 1) * 32 + quad * 8 +
                        (cc & 1) * 4 + r] *
                   (-1e9f * LOG2E);
  float mx = -1e30f;
#pragma unroll
  for (int cc = 0; cc < 4; ++cc)
    mx = fmaxf(mx, fmaxf(fmaxf(sv[cc][0], sv[cc][1]),
                         fmaxf(sv[cc][2], sv[cc][3])));
  mx = fmaxf(mx, __shfl_xor(mx, 16));
  mx = fmaxf(mx, __shfl_xor(mx, 32));
  float mnew = fmaxf(m_r, mx);
  float alpha = ex2(m_r - mnew);
  m_r = mnew;
  float rs = 0.f;
  u16x4 pk[4];
#pragma unroll
  for (int cc = 0; cc < 4; ++cc) {
    float p0 = ex2(sv[cc][0] - m_r), p1 = ex2(sv[cc][1] - m_r);
    float p2 = ex2(sv[cc][2] - m_r), p3 = ex2(sv[cc][3] - m_r);
    rs += (p0 + p1) + (p2 + p3);
    pk[cc] = pack4(p0, p1, p2, p3);
  }
  rs += __shfl_xor(rs, 16);
  rs += __shfl_xor(rs, 32);
  l_r = l_r * alpha + rs;
  float a4[4];
#pragma unroll
  for (int r = 0; r < 4; ++r)
    a4[r] = __shfl(alpha, (lane & 48) | (quad * 4 + r));
#pragma unroll
  for (int nt = 0; nt < 4; ++nt)
#pragma unroll
    for (int r = 0; r < 4; ++r) o[nt][r] *= a4[r];
  __builtin_amdgcn_s_setprio(1);
#pragma unroll
  for (int g = 0; g < 2; ++g) {
    bf16x8 pa = cat8(pk[g * 2], pk[g * 2 + 1]);
#pragma unroll
    for (int nt = 0; nt < 4; ++nt) {
      const u16* vb = &Vt[(((g * 8 + quad * 2) * 64) + nt * 16 + l16) * 4];
      bf16x8 vf = cat8(*(const u16x4*)vb, *(const u16x4*)(vb + 256));
      o[nt] = mfma32(pa, vf, o[nt]);
    }
  }
  __builtin_amdgcn_s_setprio(0);
  __syncthreads();
}

__global__ __launch_bounds__(512, 4) void flash_attn(
    const u16* __restrict__ Qh, const u16* __restrict__ Khs,
    const u16* __restrict__ Vhs, const float* __restrict__ mask,
    const int* __restrict__ flag, u16* __restrict__ Ob) {
  int L = blockIdx.x + (blockIdx.y << 4);   // grid (16,32): L in [0,512)
  int bh = (L & 7) * 4 + ((L >> 3) & 3);    // XCD-confined bh group
  int q0 = (L >> 5) * 128;
  int t = threadIdx.x, w = t >> 6, lane = t & 63;
  int quad = lane >> 4, l16 = lane & 15;
  __shared__ u16 SMEM[16384];  // Kb[2][4096] | Vb[2][4096] = 32 KB
  u16* Kb0 = SMEM;
  u16* Vb0 = SMEM + 8192;
  const u16* Kg0 = Khs + (u64)bh * 32 * 4096;
  const u16* Vg0 = Vhs + (u64)bh * 32 * 4096;
  const u16* Qbase = Qh + ((u64)bh * 2048 + q0 + w * 16 + l16) * 64 + quad * 8;
  bf16x8 aq0 = ld_bf8(Qbase);
  bf16x8 aq1 = ld_bf8(Qbase + 32);
  f32x4 o[4] = {};
  const bool use_mask = (*flag) != 0;
  int x7 = l16 & 7;
  const u16x8 ones8u = {0x3F80, 0x3F80, 0x3F80, 0x3F80,
                        0x3F80, 0x3F80, 0x3F80, 0x3F80};
  bf16x8 ones8 = __builtin_bit_cast(bf16x8, ones8u);
  // stage tile 0: one K + one V granule per thread
  gll16(Kg0 + t * 8, &Kb0[t * 8]);
  gll16(Vg0 + t * 8, &Vb0[t * 8]);
  __syncthreads();
  int b = bh >> 4, h = bh & 15;
  if (!use_mask) {
    f32x4 l_acc = {};
    for (int T = 0; T < 32; T += 2) {
      fa_fast_step<0>(T, t, quad, l16, x7, Kg0, Vg0, Kb0, Vb0, aq0, aq1, o,
                      l_acc, ones8);
      fa_fast_step<1>(T + 1, t, quad, l16, x7, Kg0, Vg0, Kb0, Vb0, aq0, aq1,
                      o, l_acc, ones8);
    }
    float rl[4];
#pragma unroll
    for (int r = 0; r < 4; ++r) rl[r] = 1.f / l_acc[r];
#pragma unroll
    for (int nt = 0; nt < 4; ++nt)
#pragma unroll
      for (int r = 0; r < 4; ++r) {
        int srow = q0 + w * 16 + quad * 4 + r;
        Ob[(u64)(b * 2048 + srow) * 1024 + h * 64 + nt * 16 + l16] =
            f2bf(o[nt][r] * rl[r]);
      }
  } else {
    float m_r = -1e30f, l_r = 0.f;  // per-lane softmax state for q = l16
    int qg = q0 + w * 16 + l16;
    for (int T = 0; T < 32; T += 2) {
      fa_mask_step<0>(T, t, lane, quad, l16, x7, qg, Kg0, Vg0, mask, Kb0, Vb0,
                      aq0, aq1, o, m_r, l_r);
      fa_mask_step<1>(T + 1, t, lane, quad, l16, x7, qg, Kg0, Vg0, mask, Kb0,
                      Vb0, aq0, aq1, o, m_r, l_r);
    }
    float rl[4];
#pragma unroll
    for (int r = 0; r < 4; ++r)
      rl[r] = 1.f / __shfl(l_r, (lane & 48) | (quad * 4 + r));
#pragma unroll
    for (int nt = 0; nt < 4; ++nt)
#pragma unroll
      for (int r = 0; r < 4; ++r) {
        int srow = q0 + w * 16 + quad * 4 + r;
        Ob[(u64)(b * 2048 + srow) * 1024 + h * 64 + nt * 16 + l16] =
            f2bf(o[nt][r] * rl[r]);
      }
  }
}

// ---------------- kernel 4: output projection (BK=64, 2-phase) ------------
__global__ __launch_bounds__(256, 2) void out_gemm(const u16* __restrict__ Ob,
                                                   const u16* __restrict__ woT,
                                                   const float* __restrict__ bo,
                                                   float* __restrict__ out) {
  int m0 = blockIdx.x * 128, n0 = blockIdx.y * 64;
  __shared__ __align__(16) u16 SH[24576];  // 2 stages x (A 8192 + B 4096)
  f32x4 acc[2][4] = {};
  int t = threadIdx.x, w = t >> 6, lane = t & 63;
  int quad = lane >> 4, l16 = lane & 15;
  const u16* ag[4];
  const u16* bgp[2];
#pragma unroll
  for (int j = 0; j < 4; ++j) {
    int g = j * 256 + t, row = g >> 3, cc = (g & 7) ^ (row & 7);
    ag[j] = Ob + (u64)(m0 + row) * 1024 + cc * 8;
  }
#pragma unroll
  for (int j = 0; j < 2; ++j) {
    int g = j * 256 + t, row = g >> 3, cc = (g & 7) ^ (row & 7);
    bgp[j] = woT + (u64)(n0 + row) * 1024 + cc * 8;
  }
#define OSTAGE(buf, kt)                                              \
  {                                                                  \
    u16* D = &SH[(buf) * 12288];                                     \
    gll16(ag[0] + (kt), &D[t * 8]);                                  \
    gll16(ag[1] + (kt), &D[(256 + t) * 8]);                          \
    gll16(ag[2] + (kt), &D[(512 + t) * 8]);                          \
    gll16(ag[3] + (kt), &D[(768 + t) * 8]);                          \
    gll16(bgp[0] + (kt), &D[8192 + t * 8]);                          \
    gll16(bgp[1] + (kt), &D[8192 + (256 + t) * 8]);                  \
  }
  OSTAGE(0, 0);
  asm volatile("s_waitcnt vmcnt(0)" ::: "memory");
  __builtin_amdgcn_s_barrier();
  __builtin_amdgcn_sched_barrier(0);
#pragma unroll
  for (int T = 0; T < 16; ++T) {
    if (T + 1 < 16) { OSTAGE((T + 1) & 1, (T + 1) * 64); }
    const u16* S = SH + (T & 1) * 12288;
#pragma unroll
    for (int ks = 0; ks < 2; ++ks) {
      bf16x8 af[2], bfr[4];
#pragma unroll
      for (int i = 0; i < 2; ++i) {
        int r = w * 32 + i * 16 + l16;
        af[i] = ld_bf8(&S[(r * 8 + ((ks * 4 + quad) ^ (r & 7))) * 8]);
      }
#pragma unroll
      for (int i = 0; i < 4; ++i) {
        int r = i * 16 + l16;
        bfr[i] = ld_bf8(&S[8192 + (r * 8 + ((ks * 4 + quad) ^ (r & 7))) * 8]);
      }
#pragma unroll
      for (int mi = 0; mi < 2; ++mi)
#pragma unroll
        for (int ni = 0; ni < 4; ++ni)
          acc[mi][ni] = mfma32(af[mi], bfr[ni], acc[mi][ni]);
    }
    asm volatile("s_waitcnt vmcnt(0)" ::: "memory");
    __builtin_amdgcn_s_barrier();
    __builtin_amdgcn_sched_barrier(0);
  }
#undef OSTAGE
#pragma unroll
  for (int mi = 0; mi < 2; ++mi) {
#pragma unroll
    for (int ni = 0; ni < 4; ++ni) {
      int gn = n0 + ni * 16 + l16;
      float bv_ = bo[gn];
#pragma unroll
      for (int r = 0; r < 4; ++r) {
        int gm = m0 + w * 32 + mi * 16 + quad * 4 + r;
        out[(u64)gm * 1024 + gn] = acc[mi][ni][r] + bv_;
      }
    }
  }
}

extern "C" void kernel_launch(void* const* d_in, const int* in_sizes, int n_in,
                              void* d_out, int out_size, void* d_ws,
                              size_t ws_size, hipStream_t stream) {
  const float* q = (const float*)d_in[0];
  const float* k = (const float*)d_in[1];
  const float* v = (const float*)d_in[2];
  const float* mask = (const float*)d_in[3];
  const float* wq = (const float*)d_in[4];
  const float* bq = (const float*)d_in[5];
  const float* wk = (const float*)d_in[6];
  const float* bk = (const float*)d_in[7];
  const float* wv = (const float*)d_in[8];
  const float* bv = (const float*)d_in[9];
  const float* wo = (const float*)d_in[10];
  const float* bo = (const float*)d_in[11];
  float* out = (float*)d_out;
  char* ws = (char*)d_ws;
  const u64 MB = 1ull << 20;
  u16* qb = (u16*)(ws + 0 * MB);   // 8 MB (reused as attn output later)
  u16* kb = (u16*)(ws + 8 * MB);   // 8 MB
  u16* vb = (u16*)(ws + 16 * MB);  // 8 MB
  u16* wqT = (u16*)(ws + 24 * MB);
  u16* wkT = (u16*)(ws + 26 * MB);
  u16* wvT = (u16*)(ws + 28 * MB);
  u16* woT = (u16*)(ws + 30 * MB);
  u16* Qh = (u16*)(ws + 32 * MB);   // [32 bh][2048][64] bf16
  u16* Khs = (u16*)(ws + 40 * MB);  // [32 bh][32 tiles][4096] kkey-xor
  u16* Vhs = (u16*)(ws + 48 * MB);  // [32 bh][32 tiles][4096] 4kv-interleave
  int* flag = (int*)(ws + 56 * MB);
  int* flagArr = (int*)(ws + 56 * MB + 4096);  // 2048 ints, always stored
  u16* Ob = qb;  // alias: qb dead after qkv_gemm

  pre_kernel<<<dim3(2048, 5), 256, 0, stream>>>(
      q, k, v, mask, wq, wk, wv, wo, qb, kb, vb, wqT, wkT, wvT, woT, flagArr);
  qkv_gemm<<<dim3(32, 8, 3), 256, 0, stream>>>(qb, kb, vb, wqT, wkT, wvT, bq,
                                               bk, bv, Qh, Khs, Vhs, flagArr,
                                               flag);
  flash_attn<<<dim3(16, 32), 512, 0, stream>>>(Qh, Khs, Vhs, mask, flag, Ob);
  out_gemm<<<dim3(32, 16), 256, 0, stream>>>(Ob, woT, bo, out);
}

// Round 10
// 217.591 us; speedup vs baseline: 1.1708x; 1.0052x over previous
//
#include <hip/hip_runtime.h>

typedef unsigned short u16;
typedef unsigned int   u32;
typedef unsigned long long u64;
typedef short s16;

using f32x4  = __attribute__((ext_vector_type(4))) float;
using bf16x8 = __attribute__((ext_vector_type(8))) __bf16;
using bf16x4 = __attribute__((ext_vector_type(4))) __bf16;
using u16x8  = __attribute__((ext_vector_type(8))) u16;
using u16x4  = __attribute__((ext_vector_type(4))) u16;
using s16x4  = __attribute__((ext_vector_type(4))) s16;

#define LOG2E 1.4426950408889634f

// float -> bf16 with round-to-nearest-even (cold paths)
__device__ __forceinline__ u16 f2bf(float f) {
  u32 u = __builtin_bit_cast(u32, f);
  u32 r = u + 0x7fffu + ((u >> 16) & 1u);
  return (u16)(r >> 16);
}

// raw v_exp_f32 (OCML exp2f carries denormal fixup = ~10 VALU per call)
__device__ __forceinline__ float ex2(float x) {
#if __has_builtin(__builtin_amdgcn_exp2f)
  return __builtin_amdgcn_exp2f(x);
#else
  return exp2f(x);
#endif
}

// native __bf16 casts: compiler emits v_cvt_pk_bf16_f32 pairs
__device__ __forceinline__ u16x4 pack4(float p0, float p1, float p2, float p3) {
  bf16x4 b = {(__bf16)p0, (__bf16)p1, (__bf16)p2, (__bf16)p3};
  return __builtin_bit_cast(u16x4, b);
}

// async global->LDS, 16B per lane; LDS dest = wave-uniform base + lane*16
__device__ __forceinline__ void gll16(const u16* g, u16* l) {
  __builtin_amdgcn_global_load_lds(
      (const __attribute__((address_space(1))) void*)g,
      (__attribute__((address_space(3))) void*)l, 16, 0, 0);
}

__device__ __forceinline__ bf16x8 ld_bf8(const u16* p) {
  return __builtin_bit_cast(bf16x8, *(const u16x8*)p);
}

__device__ __forceinline__ bf16x8 cat8(u16x4 a, u16x4 b) {
  u16x8 r = {a[0], a[1], a[2], a[3], b[0], b[1], b[2], b[3]};
  return __builtin_bit_cast(bf16x8, r);
}

__device__ __forceinline__ f32x4 mfma32(bf16x8 a, bf16x8 b, f32x4 c) {
  return __builtin_amdgcn_mfma_f32_16x16x32_bf16(a, b, c, 0, 0, 0);
}

// ---- BK=32 staged-tile swizzle (bijective; global-coalesced writes,
//      2-way-free ds_read_b128): granule g holds logical (row r, chunk c):
//      r = g>>2, c = (g&3) ^ ((g>>3)&3); read offset below.
__device__ __forceinline__ int swz_r(int g) { return g >> 2; }
__device__ __forceinline__ int swz_c(int g) { return (g & 3) ^ ((g >> 3) & 3); }
__device__ __forceinline__ int swz_off(int r, int c) {  // u16 units
  return (r * 4 + (c ^ ((r >> 1) & 3))) * 8;
}

// ------------- kernel 1: fused convert + weight transpose + mask scan -----
// R8 lesson: the q/k/v f32->bf16 convert MUST stay here (BW-bound streaming
// at full TLP, and it leaves qb/kb/vb L2/L3-warm for qkv_gemm). Fusing it
// into qkv's staging regressed 45->90 us (cold-HBM latency under a short
// compute phase). Mask scan always-stores flagArr (no memset needed).
__global__ __launch_bounds__(256) void pre_kernel(
    const float* __restrict__ q, const float* __restrict__ k,
    const float* __restrict__ v, const float* __restrict__ mask,
    const float* __restrict__ wq, const float* __restrict__ wk,
    const float* __restrict__ wv, const float* __restrict__ wo,
    u16* __restrict__ qb, u16* __restrict__ kb, u16* __restrict__ vb,
    u16* __restrict__ wqT, u16* __restrict__ wkT, u16* __restrict__ wvT,
    u16* __restrict__ woT, int* __restrict__ flagArr) {
  int y = blockIdx.y, t = threadIdx.x;
  if (y < 3) {
    const float* src = y == 0 ? q : y == 1 ? k : v;
    u16* dst = y == 0 ? qb : y == 1 ? kb : vb;
    u64 i = ((u64)blockIdx.x * 256 + t) * 8;
    f32x4 a = *(const f32x4*)(src + i);
    f32x4 b = *(const f32x4*)(src + i + 4);
    u16x8 o;
    o[0] = f2bf(a[0]); o[1] = f2bf(a[1]); o[2] = f2bf(a[2]); o[3] = f2bf(a[3]);
    o[4] = f2bf(b[0]); o[5] = f2bf(b[1]); o[6] = f2bf(b[2]); o[7] = f2bf(b[3]);
    *(u16x8*)(dst + i) = o;
  } else if (y == 3) {
    __shared__ float tile[32][33];
    int x = t & 31, yy = t >> 5;  // 32 x 8
#pragma unroll
    for (int rep = 0; rep < 2; ++rep) {
      int job = blockIdx.x * 2 + rep;
      int z = job >> 10, tt = job & 1023;
      const float* W = z == 0 ? wq : z == 1 ? wk : z == 2 ? wv : wo;
      u16* WT = z == 0 ? wqT : z == 1 ? wkT : z == 2 ? wvT : woT;
      int c0 = (tt & 31) * 32, r0 = (tt >> 5) * 32;
#pragma unroll
      for (int j = 0; j < 4; ++j)
        tile[yy + j * 8][x] = W[(u64)(r0 + yy + j * 8) * 1024 + c0 + x];
      __syncthreads();
#pragma unroll
      for (int j = 0; j < 4; ++j)
        WT[(u64)(c0 + yy + j * 8) * 1024 + r0 + x] = f2bf(tile[x][yy + j * 8]);
      __syncthreads();
    }
  } else {
    u64 i = ((u64)blockIdx.x * 256 + t) * 8;
    f32x4 a = *(const f32x4*)(mask + i);
    f32x4 b = *(const f32x4*)(mask + i + 4);
    bool nz = a[0] != 0.f || a[1] != 0.f || a[2] != 0.f || a[3] != 0.f ||
              b[0] != 0.f || b[1] != 0.f || b[2] != 0.f || b[3] != 0.f;
    int bnz = __syncthreads_or(nz ? 1 : 0);
    if (t == 0) flagArr[blockIdx.x] = bnz;  // always stored: no init needed
  }
}

// ---------------- shared GEMM core (BK=32, 2-phase overlap) ---------------
// T3 minimum recipe (m248v2-verified): issue STAGE(t+1) BEFORE compute(t),
// then vmcnt(0)+barrier once per K-step. vmcnt fully drained before every
// barrier -> no writes in flight across barriers -> race-free (the R3
// counted-vmcnt schedule tripwired). Loads for t+1 fly during compute(t).
__device__ __forceinline__ void gemm_core(const u16* __restrict__ A,
                                          const u16* __restrict__ Wt, int m0,
                                          int n0, u16* SH, f32x4 acc[4][4]) {
  int t = threadIdx.x, w = t >> 6, lane = t & 63;
  int quad = lane >> 4, l16 = lane & 15;
  int wr = w >> 1, wc = w & 1;
  const u16* a0 = A + (u64)(m0 + swz_r(t)) * 1024 + swz_c(t) * 8;
  const u16* a1 = A + (u64)(m0 + swz_r(256 + t)) * 1024 + swz_c(256 + t) * 8;
  const u16* bg0 = Wt + (u64)(n0 + swz_r(t)) * 1024 + swz_c(t) * 8;
  const u16* bg1 = Wt + (u64)(n0 + swz_r(256 + t)) * 1024 + swz_c(256 + t) * 8;
  int aoff[4], boff[4];
#pragma unroll
  for (int i = 0; i < 4; ++i) {
    aoff[i] = swz_off(wr * 64 + i * 16 + l16, quad);
    boff[i] = 4096 + swz_off(wc * 64 + i * 16 + l16, quad);
  }
#define QSTAGE(buf, kt)                                         \
  gll16(a0 + (kt), &SH[(buf) * 8192 + t * 8]);                  \
  gll16(bg0 + (kt), &SH[(buf) * 8192 + 4096 + t * 8]);          \
  gll16(a1 + (kt), &SH[(buf) * 8192 + (256 + t) * 8]);          \
  gll16(bg1 + (kt), &SH[(buf) * 8192 + 4096 + (256 + t) * 8]);
  QSTAGE(0, 0);
  asm volatile("s_waitcnt vmcnt(0)" ::: "memory");
  __builtin_amdgcn_s_barrier();
  __builtin_amdgcn_sched_barrier(0);
#pragma unroll
  for (int T = 0; T < 32; ++T) {
    if (T + 1 < 32) { QSTAGE((T + 1) & 1, (T + 1) * 32); }
    const u16* S = SH + (T & 1) * 8192;
    bf16x8 af[4], bfr[4];
#pragma unroll
    for (int i = 0; i < 4; ++i) af[i] = ld_bf8(&S[aoff[i]]);
#pragma unroll
    for (int i = 0; i < 4; ++i) bfr[i] = ld_bf8(&S[boff[i]]);
#pragma unroll
    for (int mi = 0; mi < 4; ++mi)
#pragma unroll
      for (int ni = 0; ni < 4; ++ni)
        acc[mi][ni] = mfma32(af[mi], bfr[ni], acc[mi][ni]);
    asm volatile("s_waitcnt vmcnt(0)" ::: "memory");
    __builtin_amdgcn_s_barrier();
    __builtin_amdgcn_sched_barrier(0);
  }
#undef QSTAGE
}

// ---------------- kernel 2: fused QKV projection --------------------------
// K tile layout (4096 u16 per 64-kv tile), keyed on kv bits {0,1,3} so the
// PV-x32 row permutation in flash keeps the 8-slot bank spread:
//   off(kv,d) = kv*64 + ((d>>3) ^ kkey(kv))*8 + (d&7),
//   kkey(kv) = (kv&3) | ((kv>>1)&4)
// V tile layout (8-wide kv interleave so flash's PV B-operand is ONE
// ds_read_b128): off(kv,d) = ((kv>>3)*64 + d)*8 + (kv&7)
__global__ __launch_bounds__(256, 3) void qkv_gemm(
    const u16* __restrict__ qb, const u16* __restrict__ kb,
    const u16* __restrict__ vb, const u16* __restrict__ wqT,
    const u16* __restrict__ wkT, const u16* __restrict__ wvT,
    const float* __restrict__ bq, const float* __restrict__ bk,
    const float* __restrict__ bv, u16* __restrict__ Qh,
    u16* __restrict__ Khs, u16* __restrict__ Vhs,
    const int* __restrict__ flagArr, int* __restrict__ flag) {
  int z = blockIdx.z;
  const u16* A = z == 0 ? qb : z == 1 ? kb : vb;
  const u16* Wt = z == 0 ? wqT : z == 1 ? wkT : wvT;
  const float* bias = z == 0 ? bq : z == 1 ? bk : bv;
  int m0 = blockIdx.x * 128, n0 = blockIdx.y * 128;
  // 2 stage-buffers (2 x 8192 u16 = 32 KB) + headroom for the 18432-u16
  // transpose scratch reused by the epilogue.
  __shared__ __align__(16) u16 SH[18432];
  int t = threadIdx.x, w = t >> 6, lane = t & 63;
  int quad = lane >> 4, l16 = lane & 15;
  int wr = w >> 1, wc = w & 1;

  // flag OR-reduce (one block; pre completed before this kernel) [R8-verified]
  if (z == 0 && blockIdx.x == 0 && blockIdx.y == 0) {
    int v_ = 0;
#pragma unroll
    for (int i = 0; i < 8; ++i) v_ |= flagArr[t + i * 256];
    int* sred = (int*)SH;
    sred[t] = v_;
    __syncthreads();
    if (t == 0) {
      int o = 0;
      for (int i = 0; i < 256; ++i) o |= sred[i];
      *flag = o;
    }
    __syncthreads();
  }

  f32x4 acc[4][4] = {};
  gemm_core(A, Wt, m0, n0, SH, acc);
  int h = (n0 + wc * 64) >> 6;  // head, wave-uniform
  if (z == 2) {
    // V: lane's 4 r-values (kv = mi*16 + quad*4 + r) land at
    // tile[((mi*2 + (quad>>1))*64 + d)*8 + (quad&1)*4 .. +3] -> one u16x4.
#pragma unroll
    for (int mi = 0; mi < 4; ++mi) {
      int gm0 = m0 + wr * 64 + mi * 16;
      int bh = (gm0 >> 11) * 16 + h;
      int tIdx = (gm0 & 2047) >> 6;
      int kvg = mi * 2 + (quad >> 1);  // kv>>3  (gm0&63 == mi*16)
      int lo = (quad & 1) * 4;         // kv&7 base
      u16* tile = Vhs + ((u64)(bh * 32 + tIdx)) * 4096;
#pragma unroll
      for (int ni = 0; ni < 4; ++ni) {
        int d = ni * 16 + l16;
        float bv_ = bias[n0 + wc * 64 + d];
        u16x4 pv = pack4(acc[mi][ni][0] + bv_, acc[mi][ni][1] + bv_,
                         acc[mi][ni][2] + bv_, acc[mi][ni][3] + bv_);
        *(u16x4*)&tile[(kvg * 64 + d) * 8 + lo] = pv;
      }
    }
  } else {
    // Q/K: LDS transpose (rows padded to 72 u16 -> conflict-free phases),
    // then 16B granule stores (1KB contiguous per instruction).
    __syncthreads();
    u16* TB = SH + w * 2304;  // 32 rows x 72 u16 per wave
    float scale = (z == 0) ? (LOG2E / 8.f) : 1.f;
#pragma unroll
    for (int p = 0; p < 2; ++p) {
#pragma unroll
      for (int mi2 = 0; mi2 < 2; ++mi2)
#pragma unroll
        for (int ni = 0; ni < 4; ++ni) {
          int d = ni * 16 + l16;
          float bv_ = bias[n0 + wc * 64 + d];
#pragma unroll
          for (int r = 0; r < 4; ++r) {
            int kvloc = mi2 * 16 + quad * 4 + r;
            TB[kvloc * 72 + d] =
                f2bf((acc[p * 2 + mi2][ni][r] + bv_) * scale);
          }
        }
      int gm0 = m0 + wr * 64 + p * 32;
      int bh = (gm0 >> 11) * 16 + h;
#pragma unroll
      for (int i = 0; i < 4; ++i) {
        int g = i * 64 + lane;
        int kvloc = g >> 3, slot = g & 7;
        if (z == 0) {
          u16x8 gran = *(u16x8*)&TB[kvloc * 72 + slot * 8];
          int s = (gm0 & 2047) + kvloc;
          *(u16x8*)&Qh[((u64)bh * 2048 + s) * 64 + slot * 8] = gran;
        } else {
          int kk = (kvloc & 3) | ((kvloc >> 1) & 4);  // kkey(kv), bits {0,1,3}
          u16x8 gran = *(u16x8*)&TB[kvloc * 72 + (slot ^ kk) * 8];
          int tIdx = (gm0 & 2047) >> 6;
          int kv = (gm0 & 63) + kvloc;
          *(u16x8*)&Khs[((u64)(bh * 32 + tIdx)) * 4096 + kv * 64 + slot * 8] =
              gran;
        }
      }
    }
  }
}

// ---------------- kernel 3: flash attention (128q blocks, R5) -------------
// 128 q-rows x one bh per block; 8 waves = 8 q-strips of 16 rows, each wave
// consumes the FULL 64-kv tile. PV runs on 16x16x32 MFMA: QK chunk cc loads
// K rows kvr = (cc>>1)*32 + (l16>>2)*8 + (cc&1)*4 + (l16&3), so the S
// fragment pair [pk[2g], pk[2g+1]] is exactly the x32 A-operand
// (kv = g*32 + quad*8 + 0..7) -- no shuffles. kkey makes x7 = l16&7 still.
// V's 8-wide interleave makes the PV B-operand one ds_read_b128 (bank-
// minimal: 8 lanes/bank = the 1024B floor).
// NOTE (R6 lesson): splitting to 64q/4-wave blocks REGRESSED (47.3 vs 44.8);
// flash's limiter is the per-step serial chain, not wave-count.
// launch_bounds (512,2): grid = 2 blocks/CU (16 waves) anyway; the old
// (512,4) capped VGPR at 64 (measured 56) and forced per-iteration address
// remat -> VALU bloat. 128-VGPR cap still guarantees 2 blocks/CU.
template <int CUR>
__device__ __forceinline__ void fa_fast_step(
    int T, int t, int quad, int l16, int x7,
    const u16* __restrict__ Kg0, const u16* __restrict__ Vg0, u16* Kb0,
    u16* Vb0, bf16x8 aq0, bf16x8 aq1, f32x4 (&o)[4], f32x4& l_acc,
    bf16x8 ones8) {
  if (T + 1 < 32) {
    gll16(Kg0 + (u64)(T + 1) * 4096 + t * 8, &Kb0[(CUR ^ 1) * 4096 + t * 8]);
    gll16(Vg0 + (u64)(T + 1) * 4096 + t * 8, &Vb0[(CUR ^ 1) * 4096 + t * 8]);
  }
  const u16* Kt = Kb0 + CUR * 4096;
  const u16* Vt = Vb0 + CUR * 4096;
  int lbase = (l16 >> 2) * 8 + (l16 & 3);
  u16x4 pk[4];
#pragma unroll
  for (int cc = 0; cc < 4; ++cc) {
    int kvr = (cc >> 1) * 32 + (cc & 1) * 4 + lbase;
    bf16x8 k0 = ld_bf8(&Kt[kvr * 64 + ((quad ^ x7)) * 8]);
    bf16x8 k1 = ld_bf8(&Kt[kvr * 64 + (((quad + 4) ^ x7)) * 8]);
    f32x4 s_ = {};
    s_ = mfma32(k0, aq0, s_);
    s_ = mfma32(k1, aq1, s_);
    pk[cc] = pack4(ex2(s_[0]), ex2(s_[1]), ex2(s_[2]), ex2(s_[3]));
  }
  __builtin_amdgcn_s_setprio(1);
#pragma unroll
  for (int g = 0; g < 2; ++g) {
    bf16x8 pa = cat8(pk[g * 2], pk[g * 2 + 1]);
    l_acc = mfma32(pa, ones8, l_acc);
#pragma unroll
    for (int nt = 0; nt < 4; ++nt) {
      bf16x8 vf = ld_bf8(&Vt[((g * 4 + quad) * 64 + nt * 16 + l16) * 8]);
      o[nt] = mfma32(pa, vf, o[nt]);
    }
  }
  __builtin_amdgcn_s_setprio(0);
  __syncthreads();
}

template <int CUR>
__device__ __forceinline__ void fa_mask_step(
    int T, int t, int lane, int quad, int l16, int x7, int qg,
    const u16* __restrict__ Kg0, const u16* __restrict__ Vg0,
    const float* __restrict__ mask, u16* Kb0, u16* Vb0, bf16x8 aq0,
    bf16x8 aq1, f32x4 (&o)[4], float& m_r, float& l_r) {
  if (T + 1 < 32) {
    gll16(Kg0 + (u64)(T + 1) * 4096 + t * 8, &Kb0[(CUR ^ 1) * 4096 + t * 8]);
    gll16(Vg0 + (u64)(T + 1) * 4096 + t * 8, &Vb0[(CUR ^ 1) * 4096 + t * 8]);
  }
  const u16* Kt = Kb0 + CUR * 4096;
  const u16* Vt = Vb0 + CUR * 4096;
  int lbase = (l16 >> 2) * 8 + (l16 & 3);
  f32x4 sv[4];
#pragma unroll
  for (int cc = 0; cc < 4; ++cc) {
    int kvr = (cc >> 1) * 32 + (cc & 1) * 4 + lbase;
    bf16x8 k0 = ld_bf8(&Kt[kvr * 64 + ((quad ^ x7)) * 8]);
    bf16x8 k1 = ld_bf8(&Kt[kvr * 64 + (((quad + 4) ^ x7)) * 8]);
    f32x4 s_ = {};
    s_ = mfma32(k0, aq0, s_);
    s_ = mfma32(k1, aq1, s_);
    sv[cc] = s_;
  }
  // D-row quad*4+r of chunk cc holds kv = (cc>>1)*32 + quad*8 + (cc&1)*4 + r
#pragma unroll
  for (int cc = 0; cc < 4; ++cc)
#pragma unroll
    for (int r = 0; r < 4; ++r)
      sv[cc][r] += mask[(u64)qg * 2048 + T * 64 + (cc >> 1) * 32 + quad * 8 +
                        (cc & 1) * 4 + r] *
                   (-1e9f * LOG2E);
  float mx = -1e30f;
#pragma unroll
  for (int cc = 0; cc < 4; ++cc)
    mx = fmaxf(mx, fmaxf(fmaxf(sv[cc][0], sv[cc][1]),
                         fmaxf(sv[cc][2], sv[cc][3])));
  mx = fmaxf(mx, __shfl_xor(mx, 16));
  mx = fmaxf(mx, __shfl_xor(mx, 32));
  float mnew = fmaxf(m_r, mx);
  float alpha = ex2(m_r - mnew);
  m_r = mnew;
  float rs = 0.f;
  u16x4 pk[4];
#pragma unroll
  for (int cc = 0; cc < 4; ++cc) {
    float p0 = ex2(sv[cc][0] - m_r), p1 = ex2(sv[cc][1] - m_r);
    float p2 = ex2(sv[cc][2] - m_r), p3 = ex2(sv[cc][3] - m_r);
    rs += (p0 + p1) + (p2 + p3);
    pk[cc] = pack4(p0, p1, p2, p3);
  }
  rs += __shfl_xor(rs, 16);
  rs += __shfl_xor(rs, 32);
  l_r = l_r * alpha + rs;
  float a4[4];
#pragma unroll
  for (int r = 0; r < 4; ++r)
    a4[r] = __shfl(alpha, (lane & 48) | (quad * 4 + r));
#pragma unroll
  for (int nt = 0; nt < 4; ++nt)
#pragma unroll
    for (int r = 0; r < 4; ++r) o[nt][r] *= a4[r];
  __builtin_amdgcn_s_setprio(1);
#pragma unroll
  for (int g = 0; g < 2; ++g) {
    bf16x8 pa = cat8(pk[g * 2], pk[g * 2 + 1]);
#pragma unroll
    for (int nt = 0; nt < 4; ++nt) {
      bf16x8 vf = ld_bf8(&Vt[((g * 4 + quad) * 64 + nt * 16 + l16) * 8]);
      o[nt] = mfma32(pa, vf, o[nt]);
    }
  }
  __builtin_amdgcn_s_setprio(0);
  __syncthreads();
}

__global__ __launch_bounds__(512, 2) void flash_attn(
    const u16* __restrict__ Qh, const u16* __restrict__ Khs,
    const u16* __restrict__ Vhs, const float* __restrict__ mask,
    const int* __restrict__ flag, u16* __restrict__ Ob) {
  int L = blockIdx.x + (blockIdx.y << 4);   // grid (16,32): L in [0,512)
  int bh = (L & 7) * 4 + ((L >> 3) & 3);    // XCD-confined bh group
  int q0 = (L >> 5) * 128;
  int t = threadIdx.x, w = t >> 6, lane = t & 63;
  int quad = lane >> 4, l16 = lane & 15;
  __shared__ u16 SMEM[16384];  // Kb[2][4096] | Vb[2][4096] = 32 KB
  u16* Kb0 = SMEM;
  u16* Vb0 = SMEM + 8192;
  const u16* Kg0 = Khs + (u64)bh * 32 * 4096;
  const u16* Vg0 = Vhs + (u64)bh * 32 * 4096;
  const u16* Qbase = Qh + ((u64)bh * 2048 + q0 + w * 16 + l16) * 64 + quad * 8;
  bf16x8 aq0 = ld_bf8(Qbase);
  bf16x8 aq1 = ld_bf8(Qbase + 32);
  f32x4 o[4] = {};
  const bool use_mask = (*flag) != 0;
  int x7 = l16 & 7;
  const u16x8 ones8u = {0x3F80, 0x3F80, 0x3F80, 0x3F80,
                        0x3F80, 0x3F80, 0x3F80, 0x3F80};
  bf16x8 ones8 = __builtin_bit_cast(bf16x8, ones8u);
  // stage tile 0: one K + one V granule per thread
  gll16(Kg0 + t * 8, &Kb0[t * 8]);
  gll16(Vg0 + t * 8, &Vb0[t * 8]);
  __syncthreads();
  int b = bh >> 4, h = bh & 15;
  if (!use_mask) {
    f32x4 l_acc = {};
    for (int T = 0; T < 32; T += 2) {
      fa_fast_step<0>(T, t, quad, l16, x7, Kg0, Vg0, Kb0, Vb0, aq0, aq1, o,
                      l_acc, ones8);
      fa_fast_step<1>(T + 1, t, quad, l16, x7, Kg0, Vg0, Kb0, Vb0, aq0, aq1,
                      o, l_acc, ones8);
    }
    float rl[4];
#pragma unroll
    for (int r = 0; r < 4; ++r) rl[r] = 1.f / l_acc[r];
#pragma unroll
    for (int nt = 0; nt < 4; ++nt)
#pragma unroll
      for (int r = 0; r < 4; ++r) {
        int srow = q0 + w * 16 + quad * 4 + r;
        Ob[(u64)(b * 2048 + srow) * 1024 + h * 64 + nt * 16 + l16] =
            f2bf(o[nt][r] * rl[r]);
      }
  } else {
    float m_r = -1e30f, l_r = 0.f;  // per-lane softmax state for q = l16
    int qg = q0 + w * 16 + l16;
    for (int T = 0; T < 32; T += 2) {
      fa_mask_step<0>(T, t, lane, quad, l16, x7, qg, Kg0, Vg0, mask, Kb0, Vb0,
                      aq0, aq1, o, m_r, l_r);
      fa_mask_step<1>(T + 1, t, lane, quad, l16, x7, qg, Kg0, Vg0, mask, Kb0,
                      Vb0, aq0, aq1, o, m_r, l_r);
    }
    float rl[4];
#pragma unroll
    for (int r = 0; r < 4; ++r)
      rl[r] = 1.f / __shfl(l_r, (lane & 48) | (quad * 4 + r));
#pragma unroll
    for (int nt = 0; nt < 4; ++nt)
#pragma unroll
      for (int r = 0; r < 4; ++r) {
        int srow = q0 + w * 16 + quad * 4 + r;
        Ob[(u64)(b * 2048 + srow) * 1024 + h * 64 + nt * 16 + l16] =
            f2bf(o[nt][r] * rl[r]);
      }
  }
}

// ---------------- kernel 4: output projection (BK=64, 2-phase) ------------
__global__ __launch_bounds__(256, 2) void out_gemm(const u16* __restrict__ Ob,
                                                   const u16* __restrict__ woT,
                                                   const float* __restrict__ bo,
                                                   float* __restrict__ out) {
  int m0 = blockIdx.x * 128, n0 = blockIdx.y * 64;
  __shared__ __align__(16) u16 SH[24576];  // 2 stages x (A 8192 + B 4096)
  f32x4 acc[2][4] = {};
  int t = threadIdx.x, w = t >> 6, lane = t & 63;
  int quad = lane >> 4, l16 = lane & 15;
  const u16* ag[4];
  const u16* bgp[2];
#pragma unroll
  for (int j = 0; j < 4; ++j) {
    int g = j * 256 + t, row = g >> 3, cc = (g & 7) ^ (row & 7);
    ag[j] = Ob + (u64)(m0 + row) * 1024 + cc * 8;
  }
#pragma unroll
  for (int j = 0; j < 2; ++j) {
    int g = j * 256 + t, row = g >> 3, cc = (g & 7) ^ (row & 7);
    bgp[j] = woT + (u64)(n0 + row) * 1024 + cc * 8;
  }
#define OSTAGE(buf, kt)                                              \
  {                                                                  \
    u16* D = &SH[(buf) * 12288];                                     \
    gll16(ag[0] + (kt), &D[t * 8]);                                  \
    gll16(ag[1] + (kt), &D[(256 + t) * 8]);                          \
    gll16(ag[2] + (kt), &D[(512 + t) * 8]);                          \
    gll16(ag[3] + (kt), &D[(768 + t) * 8]);                          \
    gll16(bgp[0] + (kt), &D[8192 + t * 8]);                          \
    gll16(bgp[1] + (kt), &D[8192 + (256 + t) * 8]);                  \
  }
  OSTAGE(0, 0);
  asm volatile("s_waitcnt vmcnt(0)" ::: "memory");
  __builtin_amdgcn_s_barrier();
  __builtin_amdgcn_sched_barrier(0);
#pragma unroll
  for (int T = 0; T < 16; ++T) {
    if (T + 1 < 16) { OSTAGE((T + 1) & 1, (T + 1) * 64); }
    const u16* S = SH + (T & 1) * 12288;
#pragma unroll
    for (int ks = 0; ks < 2; ++ks) {
      bf16x8 af[2], bfr[4];
#pragma unroll
      for (int i = 0; i < 2; ++i) {
        int r = w * 32 + i * 16 + l16;
        af[i] = ld_bf8(&S[(r * 8 + ((ks * 4 + quad) ^ (r & 7))) * 8]);
      }
#pragma unroll
      for (int i = 0; i < 4; ++i) {
        int r = i * 16 + l16;
        bfr[i] = ld_bf8(&S[8192 + (r * 8 + ((ks * 4 + quad) ^ (r & 7))) * 8]);
      }
#pragma unroll
      for (int mi = 0; mi < 2; ++mi)
#pragma unroll
        for (int ni = 0; ni < 4; ++ni)
          acc[mi][ni] = mfma32(af[mi], bfr[ni], acc[mi][ni]);
    }
    asm volatile("s_waitcnt vmcnt(0)" ::: "memory");
    __builtin_amdgcn_s_barrier();
    __builtin_amdgcn_sched_barrier(0);
  }
#undef OSTAGE
#pragma unroll
  for (int mi = 0; mi < 2; ++mi) {
#pragma unroll
    for (int ni = 0; ni < 4; ++ni) {
      int gn = n0 + ni * 16 + l16;
      float bv_ = bo[gn];
#pragma unroll
      for (int r = 0; r < 4; ++r) {
        int gm = m0 + w * 32 + mi * 16 + quad * 4 + r;
        out[(u64)gm * 1024 + gn] = acc[mi][ni][r] + bv_;
      }
    }
  }
}

extern "C" void kernel_launch(void* const* d_in, const int* in_sizes, int n_in,
                              void* d_out, int out_size, void* d_ws,
                              size_t ws_size, hipStream_t stream) {
  const float* q = (const float*)d_in[0];
  const float* k = (const float*)d_in[1];
  const float* v = (const float*)d_in[2];
  const float* mask = (const float*)d_in[3];
  const float* wq = (const float*)d_in[4];
  const float* bq = (const float*)d_in[5];
  const float* wk = (const float*)d_in[6];
  const float* bk = (const float*)d_in[7];
  const float* wv = (const float*)d_in[8];
  const float* bv = (const float*)d_in[9];
  const float* wo = (const float*)d_in[10];
  const float* bo = (const float*)d_in[11];
  float* out = (float*)d_out;
  char* ws = (char*)d_ws;
  const u64 MB = 1ull << 20;
  u16* qb = (u16*)(ws + 0 * MB);   // 8 MB (reused as attn output later)
  u16* kb = (u16*)(ws + 8 * MB);   // 8 MB
  u16* vb = (u16*)(ws + 16 * MB);  // 8 MB
  u16* wqT = (u16*)(ws + 24 * MB);
  u16* wkT = (u16*)(ws + 26 * MB);
  u16* wvT = (u16*)(ws + 28 * MB);
  u16* woT = (u16*)(ws + 30 * MB);
  u16* Qh = (u16*)(ws + 32 * MB);   // [32 bh][2048][64] bf16
  u16* Khs = (u16*)(ws + 40 * MB);  // [32 bh][32 tiles][4096] kkey-xor
  u16* Vhs = (u16*)(ws + 48 * MB);  // [32 bh][32 tiles][4096] 8kv-interleave
  int* flag = (int*)(ws + 56 * MB);
  int* flagArr = (int*)(ws + 56 * MB + 4096);  // 2048 ints, always stored
  u16* Ob = qb;  // alias: qb dead after qkv_gemm

  pre_kernel<<<dim3(2048, 5), 256, 0, stream>>>(
      q, k, v, mask, wq, wk, wv, wo, qb, kb, vb, wqT, wkT, wvT, woT, flagArr);
  qkv_gemm<<<dim3(32, 8, 3), 256, 0, stream>>>(qb, kb, vb, wqT, wkT, wvT, bq,
                                               bk, bv, Qh, Khs, Vhs, flagArr,
                                               flag);
  flash_attn<<<dim3(16, 32), 512, 0, stream>>>(Qh, Khs, Vhs, mask, flag, Ob);
  out_gemm<<<dim3(32, 16), 256, 0, stream>>>(Ob, woT, bo, out);
}

// Round 11
// 212.682 us; speedup vs baseline: 1.1979x; 1.0231x over previous
//
#include <hip/hip_runtime.h>

typedef unsigned short u16;
typedef unsigned int   u32;
typedef unsigned long long u64;
typedef short s16;

using f32x4  = __attribute__((ext_vector_type(4))) float;
using bf16x8 = __attribute__((ext_vector_type(8))) __bf16;
using bf16x4 = __attribute__((ext_vector_type(4))) __bf16;
using u16x8  = __attribute__((ext_vector_type(8))) u16;
using u16x4  = __attribute__((ext_vector_type(4))) u16;
using s16x4  = __attribute__((ext_vector_type(4))) s16;

#define LOG2E 1.4426950408889634f

// float -> bf16 with round-to-nearest-even (cold paths)
__device__ __forceinline__ u16 f2bf(float f) {
  u32 u = __builtin_bit_cast(u32, f);
  u32 r = u + 0x7fffu + ((u >> 16) & 1u);
  return (u16)(r >> 16);
}

// raw v_exp_f32 (OCML exp2f carries denormal fixup = ~10 VALU per call)
__device__ __forceinline__ float ex2(float x) {
#if __has_builtin(__builtin_amdgcn_exp2f)
  return __builtin_amdgcn_exp2f(x);
#else
  return exp2f(x);
#endif
}

// native __bf16 casts: compiler emits v_cvt_pk_bf16_f32 pairs
__device__ __forceinline__ u16x4 pack4(float p0, float p1, float p2, float p3) {
  bf16x4 b = {(__bf16)p0, (__bf16)p1, (__bf16)p2, (__bf16)p3};
  return __builtin_bit_cast(u16x4, b);
}

// async global->LDS, 16B per lane; LDS dest = wave-uniform base + lane*16
__device__ __forceinline__ void gll16(const u16* g, u16* l) {
  __builtin_amdgcn_global_load_lds(
      (const __attribute__((address_space(1))) void*)g,
      (__attribute__((address_space(3))) void*)l, 16, 0, 0);
}

__device__ __forceinline__ bf16x8 ld_bf8(const u16* p) {
  return __builtin_bit_cast(bf16x8, *(const u16x8*)p);
}

__device__ __forceinline__ bf16x8 cat8(u16x4 a, u16x4 b) {
  u16x8 r = {a[0], a[1], a[2], a[3], b[0], b[1], b[2], b[3]};
  return __builtin_bit_cast(bf16x8, r);
}

__device__ __forceinline__ f32x4 mfma32(bf16x8 a, bf16x8 b, f32x4 c) {
  return __builtin_amdgcn_mfma_f32_16x16x32_bf16(a, b, c, 0, 0, 0);
}

// ---- BK=32 staged-tile swizzle (bijective; global-coalesced writes,
//      2-way-free ds_read_b128): granule g holds logical (row r, chunk c):
//      r = g>>2, c = (g&3) ^ ((g>>3)&3); read offset below.
__device__ __forceinline__ int swz_r(int g) { return g >> 2; }
__device__ __forceinline__ int swz_c(int g) { return (g & 3) ^ ((g >> 3) & 3); }
__device__ __forceinline__ int swz_off(int r, int c) {  // u16 units
  return (r * 4 + (c ^ ((r >> 1) & 3))) * 8;
}

// ------------- kernel 1: fused convert + weight transpose + mask scan -----
// R8 lesson: the q/k/v f32->bf16 convert MUST stay here (BW-bound streaming
// at full TLP, and it leaves qb/kb/vb L2/L3-warm for qkv_gemm). Fusing it
// into qkv's staging regressed 45->90 us (cold-HBM latency under a short
// compute phase). Mask scan always-stores flagArr (no memset needed).
__global__ __launch_bounds__(256) void pre_kernel(
    const float* __restrict__ q, const float* __restrict__ k,
    const float* __restrict__ v, const float* __restrict__ mask,
    const float* __restrict__ wq, const float* __restrict__ wk,
    const float* __restrict__ wv, const float* __restrict__ wo,
    u16* __restrict__ qb, u16* __restrict__ kb, u16* __restrict__ vb,
    u16* __restrict__ wqT, u16* __restrict__ wkT, u16* __restrict__ wvT,
    u16* __restrict__ woT, int* __restrict__ flagArr) {
  int y = blockIdx.y, t = threadIdx.x;
  if (y < 3) {
    const float* src = y == 0 ? q : y == 1 ? k : v;
    u16* dst = y == 0 ? qb : y == 1 ? kb : vb;
    u64 i = ((u64)blockIdx.x * 256 + t) * 8;
    f32x4 a = *(const f32x4*)(src + i);
    f32x4 b = *(const f32x4*)(src + i + 4);
    u16x8 o;
    o[0] = f2bf(a[0]); o[1] = f2bf(a[1]); o[2] = f2bf(a[2]); o[3] = f2bf(a[3]);
    o[4] = f2bf(b[0]); o[5] = f2bf(b[1]); o[6] = f2bf(b[2]); o[7] = f2bf(b[3]);
    *(u16x8*)(dst + i) = o;
  } else if (y == 3) {
    __shared__ float tile[32][33];
    int x = t & 31, yy = t >> 5;  // 32 x 8
#pragma unroll
    for (int rep = 0; rep < 2; ++rep) {
      int job = blockIdx.x * 2 + rep;
      int z = job >> 10, tt = job & 1023;
      const float* W = z == 0 ? wq : z == 1 ? wk : z == 2 ? wv : wo;
      u16* WT = z == 0 ? wqT : z == 1 ? wkT : z == 2 ? wvT : woT;
      int c0 = (tt & 31) * 32, r0 = (tt >> 5) * 32;
#pragma unroll
      for (int j = 0; j < 4; ++j)
        tile[yy + j * 8][x] = W[(u64)(r0 + yy + j * 8) * 1024 + c0 + x];
      __syncthreads();
#pragma unroll
      for (int j = 0; j < 4; ++j)
        WT[(u64)(c0 + yy + j * 8) * 1024 + r0 + x] = f2bf(tile[x][yy + j * 8]);
      __syncthreads();
    }
  } else {
    u64 i = ((u64)blockIdx.x * 256 + t) * 8;
    f32x4 a = *(const f32x4*)(mask + i);
    f32x4 b = *(const f32x4*)(mask + i + 4);
    bool nz = a[0] != 0.f || a[1] != 0.f || a[2] != 0.f || a[3] != 0.f ||
              b[0] != 0.f || b[1] != 0.f || b[2] != 0.f || b[3] != 0.f;
    int bnz = __syncthreads_or(nz ? 1 : 0);
    if (t == 0) flagArr[blockIdx.x] = bnz;  // always stored: no init needed
  }
}

// ---------------- shared GEMM core (BK=32, 2-phase overlap) ---------------
// T3 minimum recipe (m248v2-verified): issue STAGE(t+1) BEFORE compute(t),
// then vmcnt(0)+barrier once per K-step. vmcnt fully drained before every
// barrier -> no writes in flight across barriers -> race-free (the R3
// counted-vmcnt schedule tripwired). Loads for t+1 fly during compute(t).
__device__ __forceinline__ void gemm_core(const u16* __restrict__ A,
                                          const u16* __restrict__ Wt, int m0,
                                          int n0, u16* SH, f32x4 acc[4][4]) {
  int t = threadIdx.x, w = t >> 6, lane = t & 63;
  int quad = lane >> 4, l16 = lane & 15;
  int wr = w >> 1, wc = w & 1;
  const u16* a0 = A + (u64)(m0 + swz_r(t)) * 1024 + swz_c(t) * 8;
  const u16* a1 = A + (u64)(m0 + swz_r(256 + t)) * 1024 + swz_c(256 + t) * 8;
  const u16* bg0 = Wt + (u64)(n0 + swz_r(t)) * 1024 + swz_c(t) * 8;
  const u16* bg1 = Wt + (u64)(n0 + swz_r(256 + t)) * 1024 + swz_c(256 + t) * 8;
  int aoff[4], boff[4];
#pragma unroll
  for (int i = 0; i < 4; ++i) {
    aoff[i] = swz_off(wr * 64 + i * 16 + l16, quad);
    boff[i] = 4096 + swz_off(wc * 64 + i * 16 + l16, quad);
  }
#define QSTAGE(buf, kt)                                         \
  gll16(a0 + (kt), &SH[(buf) * 8192 + t * 8]);                  \
  gll16(bg0 + (kt), &SH[(buf) * 8192 + 4096 + t * 8]);          \
  gll16(a1 + (kt), &SH[(buf) * 8192 + (256 + t) * 8]);          \
  gll16(bg1 + (kt), &SH[(buf) * 8192 + 4096 + (256 + t) * 8]);
  QSTAGE(0, 0);
  asm volatile("s_waitcnt vmcnt(0)" ::: "memory");
  __builtin_amdgcn_s_barrier();
  __builtin_amdgcn_sched_barrier(0);
#pragma unroll
  for (int T = 0; T < 32; ++T) {
    if (T + 1 < 32) { QSTAGE((T + 1) & 1, (T + 1) * 32); }
    const u16* S = SH + (T & 1) * 8192;
    bf16x8 af[4], bfr[4];
#pragma unroll
    for (int i = 0; i < 4; ++i) af[i] = ld_bf8(&S[aoff[i]]);
#pragma unroll
    for (int i = 0; i < 4; ++i) bfr[i] = ld_bf8(&S[boff[i]]);
#pragma unroll
    for (int mi = 0; mi < 4; ++mi)
#pragma unroll
      for (int ni = 0; ni < 4; ++ni)
        acc[mi][ni] = mfma32(af[mi], bfr[ni], acc[mi][ni]);
    asm volatile("s_waitcnt vmcnt(0)" ::: "memory");
    __builtin_amdgcn_s_barrier();
    __builtin_amdgcn_sched_barrier(0);
  }
#undef QSTAGE
}

// ---------------- kernel 2: fused QKV projection --------------------------
// K tile layout (4096 u16 per 64-kv tile), keyed on kv bits {0,1,3} so the
// PV-x32 row permutation in flash keeps the 8-slot bank spread:
//   off(kv,d) = kv*64 + ((d>>3) ^ kkey(kv))*8 + (d&7),
//   kkey(kv) = (kv&3) | ((kv>>1)&4)
// V tile layout (8-wide kv interleave so flash's PV B-operand is ONE
// ds_read_b128): off(kv,d) = ((kv>>3)*64 + d)*8 + (kv&7)
__global__ __launch_bounds__(256, 3) void qkv_gemm(
    const u16* __restrict__ qb, const u16* __restrict__ kb,
    const u16* __restrict__ vb, const u16* __restrict__ wqT,
    const u16* __restrict__ wkT, const u16* __restrict__ wvT,
    const float* __restrict__ bq, const float* __restrict__ bk,
    const float* __restrict__ bv, u16* __restrict__ Qh,
    u16* __restrict__ Khs, u16* __restrict__ Vhs,
    const int* __restrict__ flagArr, int* __restrict__ flag) {
  int z = blockIdx.z;
  const u16* A = z == 0 ? qb : z == 1 ? kb : vb;
  const u16* Wt = z == 0 ? wqT : z == 1 ? wkT : wvT;
  const float* bias = z == 0 ? bq : z == 1 ? bk : bv;
  int m0 = blockIdx.x * 128, n0 = blockIdx.y * 128;
  // 2 stage-buffers (2 x 8192 u16 = 32 KB) + headroom for the 18432-u16
  // transpose scratch reused by the epilogue.
  __shared__ __align__(16) u16 SH[18432];
  int t = threadIdx.x, w = t >> 6, lane = t & 63;
  int quad = lane >> 4, l16 = lane & 15;
  int wr = w >> 1, wc = w & 1;

  // flag OR-reduce (one block; pre completed before this kernel) [R8-verified]
  if (z == 0 && blockIdx.x == 0 && blockIdx.y == 0) {
    int v_ = 0;
#pragma unroll
    for (int i = 0; i < 8; ++i) v_ |= flagArr[t + i * 256];
    int* sred = (int*)SH;
    sred[t] = v_;
    __syncthreads();
    if (t == 0) {
      int o = 0;
      for (int i = 0; i < 256; ++i) o |= sred[i];
      *flag = o;
    }
    __syncthreads();
  }

  f32x4 acc[4][4] = {};
  gemm_core(A, Wt, m0, n0, SH, acc);
  int h = (n0 + wc * 64) >> 6;  // head, wave-uniform
  if (z == 2) {
    // V: lane's 4 r-values (kv = mi*16 + quad*4 + r) land at
    // tile[((mi*2 + (quad>>1))*64 + d)*8 + (quad&1)*4 .. +3] -> one u16x4.
#pragma unroll
    for (int mi = 0; mi < 4; ++mi) {
      int gm0 = m0 + wr * 64 + mi * 16;
      int bh = (gm0 >> 11) * 16 + h;
      int tIdx = (gm0 & 2047) >> 6;
      int kvg = mi * 2 + (quad >> 1);  // kv>>3  (gm0&63 == mi*16)
      int lo = (quad & 1) * 4;         // kv&7 base
      u16* tile = Vhs + ((u64)(bh * 32 + tIdx)) * 4096;
#pragma unroll
      for (int ni = 0; ni < 4; ++ni) {
        int d = ni * 16 + l16;
        float bv_ = bias[n0 + wc * 64 + d];
        u16x4 pv = pack4(acc[mi][ni][0] + bv_, acc[mi][ni][1] + bv_,
                         acc[mi][ni][2] + bv_, acc[mi][ni][3] + bv_);
        *(u16x4*)&tile[(kvg * 64 + d) * 8 + lo] = pv;
      }
    }
  } else {
    // Q/K: LDS transpose (rows padded to 72 u16 -> conflict-free phases),
    // then 16B granule stores (1KB contiguous per instruction).
    __syncthreads();
    u16* TB = SH + w * 2304;  // 32 rows x 72 u16 per wave
    float scale = (z == 0) ? (LOG2E / 8.f) : 1.f;
#pragma unroll
    for (int p = 0; p < 2; ++p) {
#pragma unroll
      for (int mi2 = 0; mi2 < 2; ++mi2)
#pragma unroll
        for (int ni = 0; ni < 4; ++ni) {
          int d = ni * 16 + l16;
          float bv_ = bias[n0 + wc * 64 + d];
#pragma unroll
          for (int r = 0; r < 4; ++r) {
            int kvloc = mi2 * 16 + quad * 4 + r;
            TB[kvloc * 72 + d] =
                f2bf((acc[p * 2 + mi2][ni][r] + bv_) * scale);
          }
        }
      int gm0 = m0 + wr * 64 + p * 32;
      int bh = (gm0 >> 11) * 16 + h;
#pragma unroll
      for (int i = 0; i < 4; ++i) {
        int g = i * 64 + lane;
        int kvloc = g >> 3, slot = g & 7;
        if (z == 0) {
          u16x8 gran = *(u16x8*)&TB[kvloc * 72 + slot * 8];
          int s = (gm0 & 2047) + kvloc;
          *(u16x8*)&Qh[((u64)bh * 2048 + s) * 64 + slot * 8] = gran;
        } else {
          int kk = (kvloc & 3) | ((kvloc >> 1) & 4);  // kkey(kv), bits {0,1,3}
          u16x8 gran = *(u16x8*)&TB[kvloc * 72 + (slot ^ kk) * 8];
          int tIdx = (gm0 & 2047) >> 6;
          int kv = (gm0 & 63) + kvloc;
          *(u16x8*)&Khs[((u64)(bh * 32 + tIdx)) * 4096 + kv * 64 + slot * 8] =
              gran;
        }
      }
    }
  }
}

// ---------------- kernel 3: flash attention (128q, 2 tiles/barrier) -------
// 128 q-rows x one bh per block; 8 waves = 8 q-strips of 16 rows, each wave
// consumes the FULL kv tiles. PV runs on 16x16x32 MFMA (QK row permutation
// makes [pk[2g],pk[2g+1]] the x32 A-operand; kkey keeps x7 = l16&7). V's
// 8-wide interleave makes the PV B-operand one ds_read_b128.
// R10 change: TWO kv-tiles per barrier period (64 KB LDS, still 2 blocks/CU
// at 128 KB total) -> 16 barriers instead of 32; drain amortized over 2x
// compute (same lever as out_gemm's BK=32->64, +2.7 us there). Sync is the
// verified 2-phase: vmcnt(0) before EVERY barrier, nothing in flight across.
// R6 lesson: 64q/4-wave blocks regressed; keep 8 waves.
__device__ __forceinline__ void fa_tile_fast(
    const u16* Kt, const u16* Vt, int quad, int l16, int x7, int lbase,
    bf16x8 aq0, bf16x8 aq1, f32x4 (&o)[4], f32x4& l_acc, bf16x8 ones8) {
  u16x4 pk[4];
#pragma unroll
  for (int cc = 0; cc < 4; ++cc) {
    int kvr = (cc >> 1) * 32 + (cc & 1) * 4 + lbase;
    bf16x8 k0 = ld_bf8(&Kt[kvr * 64 + ((quad ^ x7)) * 8]);
    bf16x8 k1 = ld_bf8(&Kt[kvr * 64 + (((quad + 4) ^ x7)) * 8]);
    f32x4 s_ = {};
    s_ = mfma32(k0, aq0, s_);
    s_ = mfma32(k1, aq1, s_);
    pk[cc] = pack4(ex2(s_[0]), ex2(s_[1]), ex2(s_[2]), ex2(s_[3]));
  }
  __builtin_amdgcn_s_setprio(1);
#pragma unroll
  for (int g = 0; g < 2; ++g) {
    bf16x8 pa = cat8(pk[g * 2], pk[g * 2 + 1]);
    l_acc = mfma32(pa, ones8, l_acc);
#pragma unroll
    for (int nt = 0; nt < 4; ++nt) {
      bf16x8 vf = ld_bf8(&Vt[((g * 4 + quad) * 64 + nt * 16 + l16) * 8]);
      o[nt] = mfma32(pa, vf, o[nt]);
    }
  }
  __builtin_amdgcn_s_setprio(0);
}

template <int BUF>
__device__ __forceinline__ void fa_fast_step(
    int j, int t, int quad, int l16, int x7, int lbase,
    const u16* __restrict__ Kg0, const u16* __restrict__ Vg0, u16* KB,
    u16* VB, bf16x8 aq0, bf16x8 aq1, f32x4 (&o)[4], f32x4& l_acc,
    bf16x8 ones8) {
  if (j + 1 < 16) {
    const u16* Kg = Kg0 + (u64)(2 * j + 2) * 4096;
    const u16* Vg = Vg0 + (u64)(2 * j + 2) * 4096;
    gll16(Kg + t * 8, &KB[(BUF ^ 1) * 8192 + t * 8]);
    gll16(Kg + 4096 + t * 8, &KB[(BUF ^ 1) * 8192 + 4096 + t * 8]);
    gll16(Vg + t * 8, &VB[(BUF ^ 1) * 8192 + t * 8]);
    gll16(Vg + 4096 + t * 8, &VB[(BUF ^ 1) * 8192 + 4096 + t * 8]);
  }
  fa_tile_fast(&KB[BUF * 8192], &VB[BUF * 8192], quad, l16, x7, lbase, aq0,
               aq1, o, l_acc, ones8);
  fa_tile_fast(&KB[BUF * 8192 + 4096], &VB[BUF * 8192 + 4096], quad, l16, x7,
               lbase, aq0, aq1, o, l_acc, ones8);
  asm volatile("s_waitcnt vmcnt(0)" ::: "memory");
  __builtin_amdgcn_s_barrier();
  __builtin_amdgcn_sched_barrier(0);
}

__device__ __forceinline__ void fa_tile_mask(
    int T, const u16* Kt, const u16* Vt, int lane, int quad, int l16, int x7,
    int lbase, int qg, const float* __restrict__ mask, bf16x8 aq0, bf16x8 aq1,
    f32x4 (&o)[4], float& m_r, float& l_r) {
  f32x4 sv[4];
#pragma unroll
  for (int cc = 0; cc < 4; ++cc) {
    int kvr = (cc >> 1) * 32 + (cc & 1) * 4 + lbase;
    bf16x8 k0 = ld_bf8(&Kt[kvr * 64 + ((quad ^ x7)) * 8]);
    bf16x8 k1 = ld_bf8(&Kt[kvr * 64 + (((quad + 4) ^ x7)) * 8]);
    f32x4 s_ = {};
    s_ = mfma32(k0, aq0, s_);
    s_ = mfma32(k1, aq1, s_);
    sv[cc] = s_;
  }
  // D-row quad*4+r of chunk cc holds kv = (cc>>1)*32 + quad*8 + (cc&1)*4 + r
#pragma unroll
  for (int cc = 0; cc < 4; ++cc)
#pragma unroll
    for (int r = 0; r < 4; ++r)
      sv[cc][r] += mask[(u64)qg * 2048 + T * 64 + (cc >> 1) * 32 + quad * 8 +
                        (cc & 1) * 4 + r] *
                   (-1e9f * LOG2E);
  float mx = -1e30f;
#pragma unroll
  for (int cc = 0; cc < 4; ++cc)
    mx = fmaxf(mx, fmaxf(fmaxf(sv[cc][0], sv[cc][1]),
                         fmaxf(sv[cc][2], sv[cc][3])));
  mx = fmaxf(mx, __shfl_xor(mx, 16));
  mx = fmaxf(mx, __shfl_xor(mx, 32));
  float mnew = fmaxf(m_r, mx);
  float alpha = ex2(m_r - mnew);
  m_r = mnew;
  float rs = 0.f;
  u16x4 pk[4];
#pragma unroll
  for (int cc = 0; cc < 4; ++cc) {
    float p0 = ex2(sv[cc][0] - m_r), p1 = ex2(sv[cc][1] - m_r);
    float p2 = ex2(sv[cc][2] - m_r), p3 = ex2(sv[cc][3] - m_r);
    rs += (p0 + p1) + (p2 + p3);
    pk[cc] = pack4(p0, p1, p2, p3);
  }
  rs += __shfl_xor(rs, 16);
  rs += __shfl_xor(rs, 32);
  l_r = l_r * alpha + rs;
  float a4[4];
#pragma unroll
  for (int r = 0; r < 4; ++r)
    a4[r] = __shfl(alpha, (lane & 48) | (quad * 4 + r));
#pragma unroll
  for (int nt = 0; nt < 4; ++nt)
#pragma unroll
    for (int r = 0; r < 4; ++r) o[nt][r] *= a4[r];
  __builtin_amdgcn_s_setprio(1);
#pragma unroll
  for (int g = 0; g < 2; ++g) {
    bf16x8 pa = cat8(pk[g * 2], pk[g * 2 + 1]);
#pragma unroll
    for (int nt = 0; nt < 4; ++nt) {
      bf16x8 vf = ld_bf8(&Vt[((g * 4 + quad) * 64 + nt * 16 + l16) * 8]);
      o[nt] = mfma32(pa, vf, o[nt]);
    }
  }
  __builtin_amdgcn_s_setprio(0);
}

template <int BUF>
__device__ __forceinline__ void fa_mask_step(
    int j, int t, int lane, int quad, int l16, int x7, int lbase, int qg,
    const u16* __restrict__ Kg0, const u16* __restrict__ Vg0,
    const float* __restrict__ mask, u16* KB, u16* VB, bf16x8 aq0, bf16x8 aq1,
    f32x4 (&o)[4], float& m_r, float& l_r) {
  if (j + 1 < 16) {
    const u16* Kg = Kg0 + (u64)(2 * j + 2) * 4096;
    const u16* Vg = Vg0 + (u64)(2 * j + 2) * 4096;
    gll16(Kg + t * 8, &KB[(BUF ^ 1) * 8192 + t * 8]);
    gll16(Kg + 4096 + t * 8, &KB[(BUF ^ 1) * 8192 + 4096 + t * 8]);
    gll16(Vg + t * 8, &VB[(BUF ^ 1) * 8192 + t * 8]);
    gll16(Vg + 4096 + t * 8, &VB[(BUF ^ 1) * 8192 + 4096 + t * 8]);
  }
  fa_tile_mask(2 * j, &KB[BUF * 8192], &VB[BUF * 8192], lane, quad, l16, x7,
               lbase, qg, mask, aq0, aq1, o, m_r, l_r);
  fa_tile_mask(2 * j + 1, &KB[BUF * 8192 + 4096], &VB[BUF * 8192 + 4096],
               lane, quad, l16, x7, lbase, qg, mask, aq0, aq1, o, m_r, l_r);
  asm volatile("s_waitcnt vmcnt(0)" ::: "memory");
  __builtin_amdgcn_s_barrier();
  __builtin_amdgcn_sched_barrier(0);
}

__global__ __launch_bounds__(512, 2) void flash_attn(
    const u16* __restrict__ Qh, const u16* __restrict__ Khs,
    const u16* __restrict__ Vhs, const float* __restrict__ mask,
    const int* __restrict__ flag, u16* __restrict__ Ob) {
  int L = blockIdx.x + (blockIdx.y << 4);   // grid (16,32): L in [0,512)
  int bh = (L & 7) * 4 + ((L >> 3) & 3);    // XCD-confined bh group
  int q0 = (L >> 5) * 128;
  int t = threadIdx.x, w = t >> 6, lane = t & 63;
  int quad = lane >> 4, l16 = lane & 15;
  __shared__ u16 SMEM[32768];  // KB[2][8192] | VB[2][8192] = 64 KB
  u16* KB = SMEM;
  u16* VB = SMEM + 16384;
  const u16* Kg0 = Khs + (u64)bh * 32 * 4096;
  const u16* Vg0 = Vhs + (u64)bh * 32 * 4096;
  const u16* Qbase = Qh + ((u64)bh * 2048 + q0 + w * 16 + l16) * 64 + quad * 8;
  bf16x8 aq0 = ld_bf8(Qbase);
  bf16x8 aq1 = ld_bf8(Qbase + 32);
  f32x4 o[4] = {};
  const bool use_mask = (*flag) != 0;
  int x7 = l16 & 7;
  int lbase = (l16 >> 2) * 8 + (l16 & 3);
  const u16x8 ones8u = {0x3F80, 0x3F80, 0x3F80, 0x3F80,
                        0x3F80, 0x3F80, 0x3F80, 0x3F80};
  bf16x8 ones8 = __builtin_bit_cast(bf16x8, ones8u);
  // stage tiles 0,1 into buf0: two K + two V granules per thread
  gll16(Kg0 + t * 8, &KB[t * 8]);
  gll16(Kg0 + 4096 + t * 8, &KB[4096 + t * 8]);
  gll16(Vg0 + t * 8, &VB[t * 8]);
  gll16(Vg0 + 4096 + t * 8, &VB[4096 + t * 8]);
  asm volatile("s_waitcnt vmcnt(0)" ::: "memory");
  __builtin_amdgcn_s_barrier();
  __builtin_amdgcn_sched_barrier(0);
  int b = bh >> 4, h = bh & 15;
  if (!use_mask) {
    f32x4 l_acc = {};
    for (int j = 0; j < 16; j += 2) {
      fa_fast_step<0>(j, t, quad, l16, x7, lbase, Kg0, Vg0, KB, VB, aq0, aq1,
                      o, l_acc, ones8);
      fa_fast_step<1>(j + 1, t, quad, l16, x7, lbase, Kg0, Vg0, KB, VB, aq0,
                      aq1, o, l_acc, ones8);
    }
    float rl[4];
#pragma unroll
    for (int r = 0; r < 4; ++r) rl[r] = 1.f / l_acc[r];
#pragma unroll
    for (int nt = 0; nt < 4; ++nt)
#pragma unroll
      for (int r = 0; r < 4; ++r) {
        int srow = q0 + w * 16 + quad * 4 + r;
        Ob[(u64)(b * 2048 + srow) * 1024 + h * 64 + nt * 16 + l16] =
            f2bf(o[nt][r] * rl[r]);
      }
  } else {
    float m_r = -1e30f, l_r = 0.f;  // per-lane softmax state for q = l16
    int qg = q0 + w * 16 + l16;
    for (int j = 0; j < 16; j += 2) {
      fa_mask_step<0>(j, t, lane, quad, l16, x7, lbase, qg, Kg0, Vg0, mask,
                      KB, VB, aq0, aq1, o, m_r, l_r);
      fa_mask_step<1>(j + 1, t, lane, quad, l16, x7, lbase, qg, Kg0, Vg0,
                      mask, KB, VB, aq0, aq1, o, m_r, l_r);
    }
    float rl[4];
#pragma unroll
    for (int r = 0; r < 4; ++r)
      rl[r] = 1.f / __shfl(l_r, (lane & 48) | (quad * 4 + r));
#pragma unroll
    for (int nt = 0; nt < 4; ++nt)
#pragma unroll
      for (int r = 0; r < 4; ++r) {
        int srow = q0 + w * 16 + quad * 4 + r;
        Ob[(u64)(b * 2048 + srow) * 1024 + h * 64 + nt * 16 + l16] =
            f2bf(o[nt][r] * rl[r]);
      }
  }
}

// ---------------- kernel 4: output projection (BK=64, 2-phase) ------------
__global__ __launch_bounds__(256, 2) void out_gemm(const u16* __restrict__ Ob,
                                                   const u16* __restrict__ woT,
                                                   const float* __restrict__ bo,
                                                   float* __restrict__ out) {
  int m0 = blockIdx.x * 128, n0 = blockIdx.y * 64;
  __shared__ __align__(16) u16 SH[24576];  // 2 stages x (A 8192 + B 4096)
  f32x4 acc[2][4] = {};
  int t = threadIdx.x, w = t >> 6, lane = t & 63;
  int quad = lane >> 4, l16 = lane & 15;
  const u16* ag[4];
  const u16* bgp[2];
#pragma unroll
  for (int j = 0; j < 4; ++j) {
    int g = j * 256 + t, row = g >> 3, cc = (g & 7) ^ (row & 7);
    ag[j] = Ob + (u64)(m0 + row) * 1024 + cc * 8;
  }
#pragma unroll
  for (int j = 0; j < 2; ++j) {
    int g = j * 256 + t, row = g >> 3, cc = (g & 7) ^ (row & 7);
    bgp[j] = woT + (u64)(n0 + row) * 1024 + cc * 8;
  }
#define OSTAGE(buf, kt)                                              \
  {                                                                  \
    u16* D = &SH[(buf) * 12288];                                     \
    gll16(ag[0] + (kt), &D[t * 8]);                                  \
    gll16(ag[1] + (kt), &D[(256 + t) * 8]);                          \
    gll16(ag[2] + (kt), &D[(512 + t) * 8]);                          \
    gll16(ag[3] + (kt), &D[(768 + t) * 8]);                          \
    gll16(bgp[0] + (kt), &D[8192 + t * 8]);                          \
    gll16(bgp[1] + (kt), &D[8192 + (256 + t) * 8]);                  \
  }
  OSTAGE(0, 0);
  asm volatile("s_waitcnt vmcnt(0)" ::: "memory");
  __builtin_amdgcn_s_barrier();
  __builtin_amdgcn_sched_barrier(0);
#pragma unroll
  for (int T = 0; T < 16; ++T) {
    if (T + 1 < 16) { OSTAGE((T + 1) & 1, (T + 1) * 64); }
    const u16* S = SH + (T & 1) * 12288;
#pragma unroll
    for (int ks = 0; ks < 2; ++ks) {
      bf16x8 af[2], bfr[4];
#pragma unroll
      for (int i = 0; i < 2; ++i) {
        int r = w * 32 + i * 16 + l16;
        af[i] = ld_bf8(&S[(r * 8 + ((ks * 4 + quad) ^ (r & 7))) * 8]);
      }
#pragma unroll
      for (int i = 0; i < 4; ++i) {
        int r = i * 16 + l16;
        bfr[i] = ld_bf8(&S[8192 + (r * 8 + ((ks * 4 + quad) ^ (r & 7))) * 8]);
      }
#pragma unroll
      for (int mi = 0; mi < 2; ++mi)
#pragma unroll
        for (int ni = 0; ni < 4; ++ni)
          acc[mi][ni] = mfma32(af[mi], bfr[ni], acc[mi][ni]);
    }
    asm volatile("s_waitcnt vmcnt(0)" ::: "memory");
    __builtin_amdgcn_s_barrier();
    __builtin_amdgcn_sched_barrier(0);
  }
#undef OSTAGE
#pragma unroll
  for (int mi = 0; mi < 2; ++mi) {
#pragma unroll
    for (int ni = 0; ni < 4; ++ni) {
      int gn = n0 + ni * 16 + l16;
      float bv_ = bo[gn];
#pragma unroll
      for (int r = 0; r < 4; ++r) {
        int gm = m0 + w * 32 + mi * 16 + quad * 4 + r;
        out[(u64)gm * 1024 + gn] = acc[mi][ni][r] + bv_;
      }
    }
  }
}

extern "C" void kernel_launch(void* const* d_in, const int* in_sizes, int n_in,
                              void* d_out, int out_size, void* d_ws,
                              size_t ws_size, hipStream_t stream) {
  const float* q = (const float*)d_in[0];
  const float* k = (const float*)d_in[1];
  const float* v = (const float*)d_in[2];
  const float* mask = (const float*)d_in[3];
  const float* wq = (const float*)d_in[4];
  const float* bq = (const float*)d_in[5];
  const float* wk = (const float*)d_in[6];
  const float* bk = (const float*)d_in[7];
  const float* wv = (const float*)d_in[8];
  const float* bv = (const float*)d_in[9];
  const float* wo = (const float*)d_in[10];
  const float* bo = (const float*)d_in[11];
  float* out = (float*)d_out;
  char* ws = (char*)d_ws;
  const u64 MB = 1ull << 20;
  u16* qb = (u16*)(ws + 0 * MB);   // 8 MB (reused as attn output later)
  u16* kb = (u16*)(ws + 8 * MB);   // 8 MB
  u16* vb = (u16*)(ws + 16 * MB);  // 8 MB
  u16* wqT = (u16*)(ws + 24 * MB);
  u16* wkT = (u16*)(ws + 26 * MB);
  u16* wvT = (u16*)(ws + 28 * MB);
  u16* woT = (u16*)(ws + 30 * MB);
  u16* Qh = (u16*)(ws + 32 * MB);   // [32 bh][2048][64] bf16
  u16* Khs = (u16*)(ws + 40 * MB);  // [32 bh][32 tiles][4096] kkey-xor
  u16* Vhs = (u16*)(ws + 48 * MB);  // [32 bh][32 tiles][4096] 8kv-interleave
  int* flag = (int*)(ws + 56 * MB);
  int* flagArr = (int*)(ws + 56 * MB + 4096);  // 2048 ints, always stored
  u16* Ob = qb;  // alias: qb dead after qkv_gemm

  pre_kernel<<<dim3(2048, 5), 256, 0, stream>>>(
      q, k, v, mask, wq, wk, wv, wo, qb, kb, vb, wqT, wkT, wvT, woT, flagArr);
  qkv_gemm<<<dim3(32, 8, 3), 256, 0, stream>>>(qb, kb, vb, wqT, wkT, wvT, bq,
                                               bk, bv, Qh, Khs, Vhs, flagArr,
                                               flag);
  flash_attn<<<dim3(16, 32), 512, 0, stream>>>(Qh, Khs, Vhs, mask, flag, Ob);
  out_gemm<<<dim3(32, 16), 256, 0, stream>>>(Ob, woT, bo, out);
}

// Round 12
// 207.193 us; speedup vs baseline: 1.2296x; 1.0265x over previous
//
#include <hip/hip_runtime.h>

typedef unsigned short u16;
typedef unsigned int   u32;
typedef unsigned long long u64;
typedef short s16;

using f32x4  = __attribute__((ext_vector_type(4))) float;
using bf16x8 = __attribute__((ext_vector_type(8))) __bf16;
using bf16x4 = __attribute__((ext_vector_type(4))) __bf16;
using u16x8  = __attribute__((ext_vector_type(8))) u16;
using u16x4  = __attribute__((ext_vector_type(4))) u16;
using s16x4  = __attribute__((ext_vector_type(4))) s16;

#define LOG2E 1.4426950408889634f

// float -> bf16 with round-to-nearest-even (cold paths)
__device__ __forceinline__ u16 f2bf(float f) {
  u32 u = __builtin_bit_cast(u32, f);
  u32 r = u + 0x7fffu + ((u >> 16) & 1u);
  return (u16)(r >> 16);
}

// raw v_exp_f32 (OCML exp2f carries denormal fixup = ~10 VALU per call)
__device__ __forceinline__ float ex2(float x) {
#if __has_builtin(__builtin_amdgcn_exp2f)
  return __builtin_amdgcn_exp2f(x);
#else
  return exp2f(x);
#endif
}

// native __bf16 casts: compiler emits v_cvt_pk_bf16_f32 pairs
__device__ __forceinline__ u16x4 pack4(float p0, float p1, float p2, float p3) {
  bf16x4 b = {(__bf16)p0, (__bf16)p1, (__bf16)p2, (__bf16)p3};
  return __builtin_bit_cast(u16x4, b);
}

// async global->LDS, 16B per lane; LDS dest = wave-uniform base + lane*16
__device__ __forceinline__ void gll16(const u16* g, u16* l) {
  __builtin_amdgcn_global_load_lds(
      (const __attribute__((address_space(1))) void*)g,
      (__attribute__((address_space(3))) void*)l, 16, 0, 0);
}

__device__ __forceinline__ bf16x8 ld_bf8(const u16* p) {
  return __builtin_bit_cast(bf16x8, *(const u16x8*)p);
}

__device__ __forceinline__ bf16x8 cat8(u16x4 a, u16x4 b) {
  u16x8 r = {a[0], a[1], a[2], a[3], b[0], b[1], b[2], b[3]};
  return __builtin_bit_cast(bf16x8, r);
}

__device__ __forceinline__ f32x4 mfma32(bf16x8 a, bf16x8 b, f32x4 c) {
  return __builtin_amdgcn_mfma_f32_16x16x32_bf16(a, b, c, 0, 0, 0);
}

// ------------- kernel 1: fused convert + weight transpose + mask scan -----
// R8 lesson: the q/k/v f32->bf16 convert MUST stay here (BW-bound streaming
// at full TLP, and it leaves qb/kb/vb L2/L3-warm for qkv_gemm). Fusing it
// into qkv's staging regressed 45->90 us (cold-HBM latency under a short
// compute phase). Mask scan always-stores flagArr (no memset needed).
__global__ __launch_bounds__(256) void pre_kernel(
    const float* __restrict__ q, const float* __restrict__ k,
    const float* __restrict__ v, const float* __restrict__ mask,
    const float* __restrict__ wq, const float* __restrict__ wk,
    const float* __restrict__ wv, const float* __restrict__ wo,
    u16* __restrict__ qb, u16* __restrict__ kb, u16* __restrict__ vb,
    u16* __restrict__ wqT, u16* __restrict__ wkT, u16* __restrict__ wvT,
    u16* __restrict__ woT, int* __restrict__ flagArr) {
  int y = blockIdx.y, t = threadIdx.x;
  if (y < 3) {
    const float* src = y == 0 ? q : y == 1 ? k : v;
    u16* dst = y == 0 ? qb : y == 1 ? kb : vb;
    u64 i = ((u64)blockIdx.x * 256 + t) * 8;
    f32x4 a = *(const f32x4*)(src + i);
    f32x4 b = *(const f32x4*)(src + i + 4);
    u16x8 o;
    o[0] = f2bf(a[0]); o[1] = f2bf(a[1]); o[2] = f2bf(a[2]); o[3] = f2bf(a[3]);
    o[4] = f2bf(b[0]); o[5] = f2bf(b[1]); o[6] = f2bf(b[2]); o[7] = f2bf(b[3]);
    *(u16x8*)(dst + i) = o;
  } else if (y == 3) {
    __shared__ float tile[32][33];
    int x = t & 31, yy = t >> 5;  // 32 x 8
#pragma unroll
    for (int rep = 0; rep < 2; ++rep) {
      int job = blockIdx.x * 2 + rep;
      int z = job >> 10, tt = job & 1023;
      const float* W = z == 0 ? wq : z == 1 ? wk : z == 2 ? wv : wo;
      u16* WT = z == 0 ? wqT : z == 1 ? wkT : z == 2 ? wvT : woT;
      int c0 = (tt & 31) * 32, r0 = (tt >> 5) * 32;
#pragma unroll
      for (int j = 0; j < 4; ++j)
        tile[yy + j * 8][x] = W[(u64)(r0 + yy + j * 8) * 1024 + c0 + x];
      __syncthreads();
#pragma unroll
      for (int j = 0; j < 4; ++j)
        WT[(u64)(c0 + yy + j * 8) * 1024 + r0 + x] = f2bf(tile[x][yy + j * 8]);
      __syncthreads();
    }
  } else {
    u64 i = ((u64)blockIdx.x * 256 + t) * 8;
    f32x4 a = *(const f32x4*)(mask + i);
    f32x4 b = *(const f32x4*)(mask + i + 4);
    bool nz = a[0] != 0.f || a[1] != 0.f || a[2] != 0.f || a[3] != 0.f ||
              b[0] != 0.f || b[1] != 0.f || b[2] != 0.f || b[3] != 0.f;
    int bnz = __syncthreads_or(nz ? 1 : 0);
    if (t == 0) flagArr[blockIdx.x] = bnz;  // always stored: no init needed
  }
}

// ---------------- kernel 2: fused QKV projection (BK=64, 2-phase) ---------
// R12 change: BK 32->64 inside the verified 2-phase template (same lever as
// out_gemm R7 and flash R10): 16 drain+barrier pairs instead of 32, 32 MFMA
// per wave per drain instead of 16. qkv's counters showed MfmaUtil 20 +
// VALU 10 = 70% idle (drain-bound, not BW: 17.9% HBM). LDS 64 KB -> 2
// blocks/CU = measured effective occupancy anyway. vmcnt(0) before every
// barrier -> nothing in flight across barriers -> race-free.
// BK=64 granule layout (R2/R7-verified): granule g -> row g>>3, slot g&7,
// src chunk slot^(row&7); read off (r*8 + ((ks*4+quad)^(r&7)))*8.
// K tile layout (4096 u16 per 64-kv tile), keyed on kv bits {0,1,3}:
//   off(kv,d) = kv*64 + ((d>>3) ^ kkey(kv))*8 + (d&7),
//   kkey(kv) = (kv&3) | ((kv>>1)&4)
// V tile layout (8-wide kv interleave so flash's PV B-operand is ONE
// ds_read_b128): off(kv,d) = ((kv>>3)*64 + d)*8 + (kv&7)
__global__ __launch_bounds__(256, 2) void qkv_gemm(
    const u16* __restrict__ qb, const u16* __restrict__ kb,
    const u16* __restrict__ vb, const u16* __restrict__ wqT,
    const u16* __restrict__ wkT, const u16* __restrict__ wvT,
    const float* __restrict__ bq, const float* __restrict__ bk,
    const float* __restrict__ bv, u16* __restrict__ Qh,
    u16* __restrict__ Khs, u16* __restrict__ Vhs,
    const int* __restrict__ flagArr, int* __restrict__ flag) {
  int z = blockIdx.z;
  const u16* A = z == 0 ? qb : z == 1 ? kb : vb;
  const u16* Wt = z == 0 ? wqT : z == 1 ? wkT : wvT;
  const float* bias = z == 0 ? bq : z == 1 ? bk : bv;
  int m0 = blockIdx.x * 128, n0 = blockIdx.y * 128;
  // 2 stages x (A 8192 + B 8192) u16 = 64 KB; epilogue transpose scratch
  // (18432 u16) reuses the front of the buffer after the K-loop.
  __shared__ __align__(16) u16 SH[32768];
  int t = threadIdx.x, w = t >> 6, lane = t & 63;
  int quad = lane >> 4, l16 = lane & 15;
  int wr = w >> 1, wc = w & 1;

  // flag OR-reduce (one block; pre completed before this kernel) [R8-verified]
  if (z == 0 && blockIdx.x == 0 && blockIdx.y == 0) {
    int v_ = 0;
#pragma unroll
    for (int i = 0; i < 8; ++i) v_ |= flagArr[t + i * 256];
    int* sred = (int*)SH;
    sred[t] = v_;
    __syncthreads();
    if (t == 0) {
      int o = 0;
      for (int i = 0; i < 256; ++i) o |= sred[i];
      *flag = o;
    }
    __syncthreads();
  }

  f32x4 acc[4][4] = {};
  {
    const u16* ag[4];
    const u16* bg[4];
#pragma unroll
    for (int j = 0; j < 4; ++j) {
      int g = j * 256 + t, row = g >> 3, cc = (g & 7) ^ (row & 7);
      ag[j] = A + (u64)(m0 + row) * 1024 + cc * 8;
      bg[j] = Wt + (u64)(n0 + row) * 1024 + cc * 8;
    }
#define QSTAGE(buf, kt)                                        \
  {                                                            \
    u16* D = &SH[(buf) * 16384];                               \
    gll16(ag[0] + (kt), &D[t * 8]);                            \
    gll16(ag[1] + (kt), &D[(256 + t) * 8]);                    \
    gll16(ag[2] + (kt), &D[(512 + t) * 8]);                    \
    gll16(ag[3] + (kt), &D[(768 + t) * 8]);                    \
    gll16(bg[0] + (kt), &D[8192 + t * 8]);                     \
    gll16(bg[1] + (kt), &D[8192 + (256 + t) * 8]);             \
    gll16(bg[2] + (kt), &D[8192 + (512 + t) * 8]);             \
    gll16(bg[3] + (kt), &D[8192 + (768 + t) * 8]);             \
  }
    QSTAGE(0, 0);
    asm volatile("s_waitcnt vmcnt(0)" ::: "memory");
    __builtin_amdgcn_s_barrier();
    __builtin_amdgcn_sched_barrier(0);
#pragma unroll
    for (int T = 0; T < 16; ++T) {
      if (T + 1 < 16) { QSTAGE((T + 1) & 1, (T + 1) * 64); }
      const u16* S = SH + (T & 1) * 16384;
#pragma unroll
      for (int ks = 0; ks < 2; ++ks) {
        bf16x8 af[4], bfr[4];
#pragma unroll
        for (int i = 0; i < 4; ++i) {
          int r = wr * 64 + i * 16 + l16;
          af[i] = ld_bf8(&S[(r * 8 + ((ks * 4 + quad) ^ (r & 7))) * 8]);
        }
#pragma unroll
        for (int i = 0; i < 4; ++i) {
          int r = wc * 64 + i * 16 + l16;
          bfr[i] =
              ld_bf8(&S[8192 + (r * 8 + ((ks * 4 + quad) ^ (r & 7))) * 8]);
        }
#pragma unroll
        for (int mi = 0; mi < 4; ++mi)
#pragma unroll
          for (int ni = 0; ni < 4; ++ni)
            acc[mi][ni] = mfma32(af[mi], bfr[ni], acc[mi][ni]);
      }
      asm volatile("s_waitcnt vmcnt(0)" ::: "memory");
      __builtin_amdgcn_s_barrier();
      __builtin_amdgcn_sched_barrier(0);
    }
#undef QSTAGE
  }

  int h = (n0 + wc * 64) >> 6;  // head, wave-uniform
  if (z == 2) {
    // V: lane's 4 r-values (kv = mi*16 + quad*4 + r) land at
    // tile[((mi*2 + (quad>>1))*64 + d)*8 + (quad&1)*4 .. +3] -> one u16x4.
#pragma unroll
    for (int mi = 0; mi < 4; ++mi) {
      int gm0 = m0 + wr * 64 + mi * 16;
      int bh = (gm0 >> 11) * 16 + h;
      int tIdx = (gm0 & 2047) >> 6;
      int kvg = mi * 2 + (quad >> 1);  // kv>>3  (gm0&63 == mi*16)
      int lo = (quad & 1) * 4;         // kv&7 base
      u16* tile = Vhs + ((u64)(bh * 32 + tIdx)) * 4096;
#pragma unroll
      for (int ni = 0; ni < 4; ++ni) {
        int d = ni * 16 + l16;
        float bv_ = bias[n0 + wc * 64 + d];
        u16x4 pv = pack4(acc[mi][ni][0] + bv_, acc[mi][ni][1] + bv_,
                         acc[mi][ni][2] + bv_, acc[mi][ni][3] + bv_);
        *(u16x4*)&tile[(kvg * 64 + d) * 8 + lo] = pv;
      }
    }
  } else {
    // Q/K: LDS transpose (rows padded to 72 u16 -> conflict-free phases),
    // then 16B granule stores (1KB contiguous per instruction).
    __syncthreads();
    u16* TB = SH + w * 2304;  // 32 rows x 72 u16 per wave
    float scale = (z == 0) ? (LOG2E / 8.f) : 1.f;
#pragma unroll
    for (int p = 0; p < 2; ++p) {
#pragma unroll
      for (int mi2 = 0; mi2 < 2; ++mi2)
#pragma unroll
        for (int ni = 0; ni < 4; ++ni) {
          int d = ni * 16 + l16;
          float bv_ = bias[n0 + wc * 64 + d];
#pragma unroll
          for (int r = 0; r < 4; ++r) {
            int kvloc = mi2 * 16 + quad * 4 + r;
            TB[kvloc * 72 + d] =
                f2bf((acc[p * 2 + mi2][ni][r] + bv_) * scale);
          }
        }
      int gm0 = m0 + wr * 64 + p * 32;
      int bh = (gm0 >> 11) * 16 + h;
#pragma unroll
      for (int i = 0; i < 4; ++i) {
        int g = i * 64 + lane;
        int kvloc = g >> 3, slot = g & 7;
        if (z == 0) {
          u16x8 gran = *(u16x8*)&TB[kvloc * 72 + slot * 8];
          int s = (gm0 & 2047) + kvloc;
          *(u16x8*)&Qh[((u64)bh * 2048 + s) * 64 + slot * 8] = gran;
        } else {
          int kk = (kvloc & 3) | ((kvloc >> 1) & 4);  // kkey(kv), bits {0,1,3}
          u16x8 gran = *(u16x8*)&TB[kvloc * 72 + (slot ^ kk) * 8];
          int tIdx = (gm0 & 2047) >> 6;
          int kv = (gm0 & 63) + kvloc;
          *(u16x8*)&Khs[((u64)(bh * 32 + tIdx)) * 4096 + kv * 64 + slot * 8] =
              gran;
        }
      }
    }
  }
}

// ---------------- kernel 3: flash attention (128q, 2 tiles/barrier) -------
// 128 q-rows x one bh per block; 8 waves = 8 q-strips of 16 rows, each wave
// consumes the FULL kv tiles. PV runs on 16x16x32 MFMA (QK row permutation
// makes [pk[2g],pk[2g+1]] the x32 A-operand; kkey keeps x7 = l16&7). V's
// 8-wide interleave makes the PV B-operand one ds_read_b128.
// TWO kv-tiles per barrier period (64 KB LDS, 2 blocks/CU at 128 KB total):
// 16 barriers instead of 32; drain amortized over 2x compute. Sync is the
// verified 2-phase: vmcnt(0) before EVERY barrier, nothing in flight across.
// R6 lesson: 64q/4-wave blocks regressed; keep 8 waves.
__device__ __forceinline__ void fa_tile_fast(
    const u16* Kt, const u16* Vt, int quad, int l16, int x7, int lbase,
    bf16x8 aq0, bf16x8 aq1, f32x4 (&o)[4], f32x4& l_acc, bf16x8 ones8) {
  u16x4 pk[4];
#pragma unroll
  for (int cc = 0; cc < 4; ++cc) {
    int kvr = (cc >> 1) * 32 + (cc & 1) * 4 + lbase;
    bf16x8 k0 = ld_bf8(&Kt[kvr * 64 + ((quad ^ x7)) * 8]);
    bf16x8 k1 = ld_bf8(&Kt[kvr * 64 + (((quad + 4) ^ x7)) * 8]);
    f32x4 s_ = {};
    s_ = mfma32(k0, aq0, s_);
    s_ = mfma32(k1, aq1, s_);
    pk[cc] = pack4(ex2(s_[0]), ex2(s_[1]), ex2(s_[2]), ex2(s_[3]));
  }
  __builtin_amdgcn_s_setprio(1);
#pragma unroll
  for (int g = 0; g < 2; ++g) {
    bf16x8 pa = cat8(pk[g * 2], pk[g * 2 + 1]);
    l_acc = mfma32(pa, ones8, l_acc);
#pragma unroll
    for (int nt = 0; nt < 4; ++nt) {
      bf16x8 vf = ld_bf8(&Vt[((g * 4 + quad) * 64 + nt * 16 + l16) * 8]);
      o[nt] = mfma32(pa, vf, o[nt]);
    }
  }
  __builtin_amdgcn_s_setprio(0);
}

template <int BUF>
__device__ __forceinline__ void fa_fast_step(
    int j, int t, int quad, int l16, int x7, int lbase,
    const u16* __restrict__ Kg0, const u16* __restrict__ Vg0, u16* KB,
    u16* VB, bf16x8 aq0, bf16x8 aq1, f32x4 (&o)[4], f32x4& l_acc,
    bf16x8 ones8) {
  if (j + 1 < 16) {
    const u16* Kg = Kg0 + (u64)(2 * j + 2) * 4096;
    const u16* Vg = Vg0 + (u64)(2 * j + 2) * 4096;
    gll16(Kg + t * 8, &KB[(BUF ^ 1) * 8192 + t * 8]);
    gll16(Kg + 4096 + t * 8, &KB[(BUF ^ 1) * 8192 + 4096 + t * 8]);
    gll16(Vg + t * 8, &VB[(BUF ^ 1) * 8192 + t * 8]);
    gll16(Vg + 4096 + t * 8, &VB[(BUF ^ 1) * 8192 + 4096 + t * 8]);
  }
  fa_tile_fast(&KB[BUF * 8192], &VB[BUF * 8192], quad, l16, x7, lbase, aq0,
               aq1, o, l_acc, ones8);
  fa_tile_fast(&KB[BUF * 8192 + 4096], &VB[BUF * 8192 + 4096], quad, l16, x7,
               lbase, aq0, aq1, o, l_acc, ones8);
  asm volatile("s_waitcnt vmcnt(0)" ::: "memory");
  __builtin_amdgcn_s_barrier();
  __builtin_amdgcn_sched_barrier(0);
}

__device__ __forceinline__ void fa_tile_mask(
    int T, const u16* Kt, const u16* Vt, int lane, int quad, int l16, int x7,
    int lbase, int qg, const float* __restrict__ mask, bf16x8 aq0, bf16x8 aq1,
    f32x4 (&o)[4], float& m_r, float& l_r) {
  f32x4 sv[4];
#pragma unroll
  for (int cc = 0; cc < 4; ++cc) {
    int kvr = (cc >> 1) * 32 + (cc & 1) * 4 + lbase;
    bf16x8 k0 = ld_bf8(&Kt[kvr * 64 + ((quad ^ x7)) * 8]);
    bf16x8 k1 = ld_bf8(&Kt[kvr * 64 + (((quad + 4) ^ x7)) * 8]);
    f32x4 s_ = {};
    s_ = mfma32(k0, aq0, s_);
    s_ = mfma32(k1, aq1, s_);
    sv[cc] = s_;
  }
  // D-row quad*4+r of chunk cc holds kv = (cc>>1)*32 + quad*8 + (cc&1)*4 + r
#pragma unroll
  for (int cc = 0; cc < 4; ++cc)
#pragma unroll
    for (int r = 0; r < 4; ++r)
      sv[cc][r] += mask[(u64)qg * 2048 + T * 64 + (cc >> 1) * 32 + quad * 8 +
                        (cc & 1) * 4 + r] *
                   (-1e9f * LOG2E);
  float mx = -1e30f;
#pragma unroll
  for (int cc = 0; cc < 4; ++cc)
    mx = fmaxf(mx, fmaxf(fmaxf(sv[cc][0], sv[cc][1]),
                         fmaxf(sv[cc][2], sv[cc][3])));
  mx = fmaxf(mx, __shfl_xor(mx, 16));
  mx = fmaxf(mx, __shfl_xor(mx, 32));
  float mnew = fmaxf(m_r, mx);
  float alpha = ex2(m_r - mnew);
  m_r = mnew;
  float rs = 0.f;
  u16x4 pk[4];
#pragma unroll
  for (int cc = 0; cc < 4; ++cc) {
    float p0 = ex2(sv[cc][0] - m_r), p1 = ex2(sv[cc][1] - m_r);
    float p2 = ex2(sv[cc][2] - m_r), p3 = ex2(sv[cc][3] - m_r);
    rs += (p0 + p1) + (p2 + p3);
    pk[cc] = pack4(p0, p1, p2, p3);
  }
  rs += __shfl_xor(rs, 16);
  rs += __shfl_xor(rs, 32);
  l_r = l_r * alpha + rs;
  float a4[4];
#pragma unroll
  for (int r = 0; r < 4; ++r)
    a4[r] = __shfl(alpha, (lane & 48) | (quad * 4 + r));
#pragma unroll
  for (int nt = 0; nt < 4; ++nt)
#pragma unroll
    for (int r = 0; r < 4; ++r) o[nt][r] *= a4[r];
  __builtin_amdgcn_s_setprio(1);
#pragma unroll
  for (int g = 0; g < 2; ++g) {
    bf16x8 pa = cat8(pk[g * 2], pk[g * 2 + 1]);
#pragma unroll
    for (int nt = 0; nt < 4; ++nt) {
      bf16x8 vf = ld_bf8(&Vt[((g * 4 + quad) * 64 + nt * 16 + l16) * 8]);
      o[nt] = mfma32(pa, vf, o[nt]);
    }
  }
  __builtin_amdgcn_s_setprio(0);
}

template <int BUF>
__device__ __forceinline__ void fa_mask_step(
    int j, int t, int lane, int quad, int l16, int x7, int lbase, int qg,
    const u16* __restrict__ Kg0, const u16* __restrict__ Vg0,
    const float* __restrict__ mask, u16* KB, u16* VB, bf16x8 aq0, bf16x8 aq1,
    f32x4 (&o)[4], float& m_r, float& l_r) {
  if (j + 1 < 16) {
    const u16* Kg = Kg0 + (u64)(2 * j + 2) * 4096;
    const u16* Vg = Vg0 + (u64)(2 * j + 2) * 4096;
    gll16(Kg + t * 8, &KB[(BUF ^ 1) * 8192 + t * 8]);
    gll16(Kg + 4096 + t * 8, &KB[(BUF ^ 1) * 8192 + 4096 + t * 8]);
    gll16(Vg + t * 8, &VB[(BUF ^ 1) * 8192 + t * 8]);
    gll16(Vg + 4096 + t * 8, &VB[(BUF ^ 1) * 8192 + 4096 + t * 8]);
  }
  fa_tile_mask(2 * j, &KB[BUF * 8192], &VB[BUF * 8192], lane, quad, l16, x7,
               lbase, qg, mask, aq0, aq1, o, m_r, l_r);
  fa_tile_mask(2 * j + 1, &KB[BUF * 8192 + 4096], &VB[BUF * 8192 + 4096],
               lane, quad, l16, x7, lbase, qg, mask, aq0, aq1, o, m_r, l_r);
  asm volatile("s_waitcnt vmcnt(0)" ::: "memory");
  __builtin_amdgcn_s_barrier();
  __builtin_amdgcn_sched_barrier(0);
}

__global__ __launch_bounds__(512, 2) void flash_attn(
    const u16* __restrict__ Qh, const u16* __restrict__ Khs,
    const u16* __restrict__ Vhs, const float* __restrict__ mask,
    const int* __restrict__ flag, u16* __restrict__ Ob) {
  int L = blockIdx.x + (blockIdx.y << 4);   // grid (16,32): L in [0,512)
  int bh = (L & 7) * 4 + ((L >> 3) & 3);    // XCD-confined bh group
  int q0 = (L >> 5) * 128;
  int t = threadIdx.x, w = t >> 6, lane = t & 63;
  int quad = lane >> 4, l16 = lane & 15;
  __shared__ u16 SMEM[32768];  // KB[2][8192] | VB[2][8192] = 64 KB
  u16* KB = SMEM;
  u16* VB = SMEM + 16384;
  const u16* Kg0 = Khs + (u64)bh * 32 * 4096;
  const u16* Vg0 = Vhs + (u64)bh * 32 * 4096;
  const u16* Qbase = Qh + ((u64)bh * 2048 + q0 + w * 16 + l16) * 64 + quad * 8;
  bf16x8 aq0 = ld_bf8(Qbase);
  bf16x8 aq1 = ld_bf8(Qbase + 32);
  f32x4 o[4] = {};
  const bool use_mask = (*flag) != 0;
  int x7 = l16 & 7;
  int lbase = (l16 >> 2) * 8 + (l16 & 3);
  const u16x8 ones8u = {0x3F80, 0x3F80, 0x3F80, 0x3F80,
                        0x3F80, 0x3F80, 0x3F80, 0x3F80};
  bf16x8 ones8 = __builtin_bit_cast(bf16x8, ones8u);
  // stage tiles 0,1 into buf0: two K + two V granules per thread
  gll16(Kg0 + t * 8, &KB[t * 8]);
  gll16(Kg0 + 4096 + t * 8, &KB[4096 + t * 8]);
  gll16(Vg0 + t * 8, &VB[t * 8]);
  gll16(Vg0 + 4096 + t * 8, &VB[4096 + t * 8]);
  asm volatile("s_waitcnt vmcnt(0)" ::: "memory");
  __builtin_amdgcn_s_barrier();
  __builtin_amdgcn_sched_barrier(0);
  int b = bh >> 4, h = bh & 15;
  if (!use_mask) {
    f32x4 l_acc = {};
    for (int j = 0; j < 16; j += 2) {
      fa_fast_step<0>(j, t, quad, l16, x7, lbase, Kg0, Vg0, KB, VB, aq0, aq1,
                      o, l_acc, ones8);
      fa_fast_step<1>(j + 1, t, quad, l16, x7, lbase, Kg0, Vg0, KB, VB, aq0,
                      aq1, o, l_acc, ones8);
    }
    float rl[4];
#pragma unroll
    for (int r = 0; r < 4; ++r) rl[r] = 1.f / l_acc[r];
#pragma unroll
    for (int nt = 0; nt < 4; ++nt)
#pragma unroll
      for (int r = 0; r < 4; ++r) {
        int srow = q0 + w * 16 + quad * 4 + r;
        Ob[(u64)(b * 2048 + srow) * 1024 + h * 64 + nt * 16 + l16] =
            f2bf(o[nt][r] * rl[r]);
      }
  } else {
    float m_r = -1e30f, l_r = 0.f;  // per-lane softmax state for q = l16
    int qg = q0 + w * 16 + l16;
    for (int j = 0; j < 16; j += 2) {
      fa_mask_step<0>(j, t, lane, quad, l16, x7, lbase, qg, Kg0, Vg0, mask,
                      KB, VB, aq0, aq1, o, m_r, l_r);
      fa_mask_step<1>(j + 1, t, lane, quad, l16, x7, lbase, qg, Kg0, Vg0,
                      mask, KB, VB, aq0, aq1, o, m_r, l_r);
    }
    float rl[4];
#pragma unroll
    for (int r = 0; r < 4; ++r)
      rl[r] = 1.f / __shfl(l_r, (lane & 48) | (quad * 4 + r));
#pragma unroll
    for (int nt = 0; nt < 4; ++nt)
#pragma unroll
      for (int r = 0; r < 4; ++r) {
        int srow = q0 + w * 16 + quad * 4 + r;
        Ob[(u64)(b * 2048 + srow) * 1024 + h * 64 + nt * 16 + l16] =
            f2bf(o[nt][r] * rl[r]);
      }
  }
}

// ---------------- kernel 4: output projection (BK=64, 2-phase) ------------
__global__ __launch_bounds__(256, 2) void out_gemm(const u16* __restrict__ Ob,
                                                   const u16* __restrict__ woT,
                                                   const float* __restrict__ bo,
                                                   float* __restrict__ out) {
  int m0 = blockIdx.x * 128, n0 = blockIdx.y * 64;
  __shared__ __align__(16) u16 SH[24576];  // 2 stages x (A 8192 + B 4096)
  f32x4 acc[2][4] = {};
  int t = threadIdx.x, w = t >> 6, lane = t & 63;
  int quad = lane >> 4, l16 = lane & 15;
  const u16* ag[4];
  const u16* bgp[2];
#pragma unroll
  for (int j = 0; j < 4; ++j) {
    int g = j * 256 + t, row = g >> 3, cc = (g & 7) ^ (row & 7);
    ag[j] = Ob + (u64)(m0 + row) * 1024 + cc * 8;
  }
#pragma unroll
  for (int j = 0; j < 2; ++j) {
    int g = j * 256 + t, row = g >> 3, cc = (g & 7) ^ (row & 7);
    bgp[j] = woT + (u64)(n0 + row) * 1024 + cc * 8;
  }
#define OSTAGE(buf, kt)                                              \
  {                                                                  \
    u16* D = &SH[(buf) * 12288];                                     \
    gll16(ag[0] + (kt), &D[t * 8]);                                  \
    gll16(ag[1] + (kt), &D[(256 + t) * 8]);                          \
    gll16(ag[2] + (kt), &D[(512 + t) * 8]);                          \
    gll16(ag[3] + (kt), &D[(768 + t) * 8]);                          \
    gll16(bgp[0] + (kt), &D[8192 + t * 8]);                          \
    gll16(bgp[1] + (kt), &D[8192 + (256 + t) * 8]);                  \
  }
  OSTAGE(0, 0);
  asm volatile("s_waitcnt vmcnt(0)" ::: "memory");
  __builtin_amdgcn_s_barrier();
  __builtin_amdgcn_sched_barrier(0);
#pragma unroll
  for (int T = 0; T < 16; ++T) {
    if (T + 1 < 16) { OSTAGE((T + 1) & 1, (T + 1) * 64); }
    const u16* S = SH + (T & 1) * 12288;
#pragma unroll
    for (int ks = 0; ks < 2; ++ks) {
      bf16x8 af[2], bfr[4];
#pragma unroll
      for (int i = 0; i < 2; ++i) {
        int r = w * 32 + i * 16 + l16;
        af[i] = ld_bf8(&S[(r * 8 + ((ks * 4 + quad) ^ (r & 7))) * 8]);
      }
#pragma unroll
      for (int i = 0; i < 4; ++i) {
        int r = i * 16 + l16;
        bfr[i] = ld_bf8(&S[8192 + (r * 8 + ((ks * 4 + quad) ^ (r & 7))) * 8]);
      }
#pragma unroll
      for (int mi = 0; mi < 2; ++mi)
#pragma unroll
        for (int ni = 0; ni < 4; ++ni)
          acc[mi][ni] = mfma32(af[mi], bfr[ni], acc[mi][ni]);
    }
    asm volatile("s_waitcnt vmcnt(0)" ::: "memory");
    __builtin_amdgcn_s_barrier();
    __builtin_amdgcn_sched_barrier(0);
  }
#undef OSTAGE
#pragma unroll
  for (int mi = 0; mi < 2; ++mi) {
#pragma unroll
    for (int ni = 0; ni < 4; ++ni) {
      int gn = n0 + ni * 16 + l16;
      float bv_ = bo[gn];
#pragma unroll
      for (int r = 0; r < 4; ++r) {
        int gm = m0 + w * 32 + mi * 16 + quad * 4 + r;
        out[(u64)gm * 1024 + gn] = acc[mi][ni][r] + bv_;
      }
    }
  }
}

extern "C" void kernel_launch(void* const* d_in, const int* in_sizes, int n_in,
                              void* d_out, int out_size, void* d_ws,
                              size_t ws_size, hipStream_t stream) {
  const float* q = (const float*)d_in[0];
  const float* k = (const float*)d_in[1];
  const float* v = (const float*)d_in[2];
  const float* mask = (const float*)d_in[3];
  const float* wq = (const float*)d_in[4];
  const float* bq = (const float*)d_in[5];
  const float* wk = (const float*)d_in[6];
  const float* bk = (const float*)d_in[7];
  const float* wv = (const float*)d_in[8];
  const float* bv = (const float*)d_in[9];
  const float* wo = (const float*)d_in[10];
  const float* bo = (const float*)d_in[11];
  float* out = (float*)d_out;
  char* ws = (char*)d_ws;
  const u64 MB = 1ull << 20;
  u16* qb = (u16*)(ws + 0 * MB);   // 8 MB (reused as attn output later)
  u16* kb = (u16*)(ws + 8 * MB);   // 8 MB
  u16* vb = (u16*)(ws + 16 * MB);  // 8 MB
  u16* wqT = (u16*)(ws + 24 * MB);
  u16* wkT = (u16*)(ws + 26 * MB);
  u16* wvT = (u16*)(ws + 28 * MB);
  u16* woT = (u16*)(ws + 30 * MB);
  u16* Qh = (u16*)(ws + 32 * MB);   // [32 bh][2048][64] bf16
  u16* Khs = (u16*)(ws + 40 * MB);  // [32 bh][32 tiles][4096] kkey-xor
  u16* Vhs = (u16*)(ws + 48 * MB);  // [32 bh][32 tiles][4096] 8kv-interleave
  int* flag = (int*)(ws + 56 * MB);
  int* flagArr = (int*)(ws + 56 * MB + 4096);  // 2048 ints, always stored
  u16* Ob = qb;  // alias: qb dead after qkv_gemm

  pre_kernel<<<dim3(2048, 5), 256, 0, stream>>>(
      q, k, v, mask, wq, wk, wv, wo, qb, kb, vb, wqT, wkT, wvT, woT, flagArr);
  qkv_gemm<<<dim3(32, 8, 3), 256, 0, stream>>>(qb, kb, vb, wqT, wkT, wvT, bq,
                                               bk, bv, Qh, Khs, Vhs, flagArr,
                                               flag);
  flash_attn<<<dim3(16, 32), 512, 0, stream>>>(Qh, Khs, Vhs, mask, flag, Ob);
  out_gemm<<<dim3(32, 16), 256, 0, stream>>>(Ob, woT, bo, out);
}